// Round 5
// baseline (213.739 us; speedup 1.0000x reference)
//
#include <hip/hip_runtime.h>
#include <hip/hip_bf16.h>

typedef __attribute__((ext_vector_type(8))) short short8;
typedef __attribute__((ext_vector_type(4))) float floatx4;

constexpr int Bsz = 4, Ssz = 1024, NXc = 1024, NHc = 16, HDc = 64;
constexpr int OUT_ELEMS  = Bsz * Ssz * NXc;        // 4194304
constexpr int HEAD_ELEMS = Bsz * NHc * Ssz * HDc;  // 4194304

union BF8 { __hip_bfloat16 h[8]; uint4 v; short8 s; };

__device__ __forceinline__ uint4 cvt8(const float* __restrict__ p) {
    float4 a = *reinterpret_cast<const float4*>(p);
    float4 b = *reinterpret_cast<const float4*>(p + 4);
    BF8 u;
    u.h[0] = __float2bfloat16(a.x); u.h[1] = __float2bfloat16(a.y);
    u.h[2] = __float2bfloat16(a.z); u.h[3] = __float2bfloat16(a.w);
    u.h[4] = __float2bfloat16(b.x); u.h[5] = __float2bfloat16(b.y);
    u.h[6] = __float2bfloat16(b.z); u.h[7] = __float2bfloat16(b.w);
    return u.v;
}

// async 16B global -> LDS (wave-uniform LDS base + lane*16)
__device__ __forceinline__ void load_lds_16B(const void* g, void* l) {
    __builtin_amdgcn_global_load_lds(
        (const __attribute__((address_space(1))) unsigned int*)g,
        (__attribute__((address_space(3))) unsigned int*)l, 16, 0, 0);
}

// ===========================================================================
// FAST PATH
// ===========================================================================

// Fused prep: x fp32->bf16 (blocks 0..2047), w_attn transpose (2048..2815),
// w_proj transpose (2816..3071).
__global__ __launch_bounds__(256) void prep_kernel(
    const float* __restrict__ x, __hip_bfloat16* __restrict__ x_bf,
    const float* __restrict__ w_attn, __hip_bfloat16* __restrict__ wTa,
    const float* __restrict__ w_proj, __hip_bfloat16* __restrict__ wTp)
{
    const int bid = blockIdx.x, tid = threadIdx.x;
    __shared__ float t[64][65];
    if (bid < 2048) {
        const int i = (bid * 256 + tid) * 8;   // covers exactly OUT_ELEMS
        *reinterpret_cast<uint4*>(x_bf + i) = cvt8(x + i);
        return;
    }
    const float* in; __hip_bfloat16* outp; int N, bx, by;
    if (bid < 2816) { const int q = bid - 2048; in = w_attn; outp = wTa; N = 3072; bx = q % 48; by = q / 48; }
    else            { const int q = bid - 2816; in = w_proj; outp = wTp; N = 1024; bx = q % 16; by = q / 16; }
    const int k0 = by * 64, n0 = bx * 64;
#pragma unroll
    for (int j = 0; j < 16; ++j) {
        const int idx = tid + j * 256;
        const int row = idx >> 6, col = idx & 63;
        t[row][col] = in[(size_t)(k0 + row) * N + n0 + col];
    }
    __syncthreads();
#pragma unroll
    for (int j = 0; j < 16; ++j) {
        const int idx = tid + j * 256;
        const int orow = idx >> 6, ocol = idx & 63;
        outp[(size_t)(n0 + orow) * 1024 + k0 + ocol] = __float2bfloat16(t[ocol][orow]);
    }
}

// ---------------------------------------------------------------------------
// 128x128-tile bf16 GEMM, BK=32, 3-buffer counted-vmcnt pipeline, LDS
// chunk-XOR swizzle (0 bank conflicts), setprio around MFMA.
// Grid is 1-D with an XCD-bijective swizzle (T1): each XCD's blocks span a
// contiguous range of A-row-panels (A L2-resident per XCD).
// EPI==0 epilogue also emits bf16 swizzled K/V tiles for attention.
// ---------------------------------------------------------------------------
template <int EPI>
__global__ __launch_bounds__(256) void gemm128p(
    const __hip_bfloat16* __restrict__ A,
    const __hip_bfloat16* __restrict__ Bt,
    const float* __restrict__ bias,
    float* __restrict__ outf,
    __hip_bfloat16* __restrict__ qws,
    float* __restrict__ present,
    __hip_bfloat16* __restrict__ kws,
    __hip_bfloat16* __restrict__ vtws,
    int M, int N, int K)
{
    __shared__ __align__(16) __hip_bfloat16 As[3][4096];
    __shared__ __align__(16) __hip_bfloat16 Bs[3][4096];

    // XCD-bijective block swizzle (nwg % 8 == 0 for both instantiations).
    const int nbx = N >> 7;
    const int nwg = (M >> 7) * nbx;
    const int wg  = blockIdx.x;
    const int swz = (wg & 7) * (nwg >> 3) + (wg >> 3);
    const int by  = swz / nbx, bx = swz % nbx;   // by-contiguous per XCD

    const int tid  = threadIdx.x;
    const int w    = tid >> 6, lane = tid & 63;
    const int quad = lane >> 4, l16 = lane & 15;
    const int m0 = by * 128, n0 = bx * 128;
    const int mb = (w >> 1) * 64, nbw = (w & 1) * 64;

    // staging: source chunk pre-swizzled so LDS position j holds chunk
    // j ^ ((row>>1)&3) (both-sides rule; LDS dest stays linear).
    const int srow = lane >> 2;
    const int sksw = (((lane & 3) ^ ((lane >> 3) & 3))) * 8;
    const int rsw = (l16 >> 1) & 3;   // fragment-read swizzle

    floatx4 acc[4][4];
#pragma unroll
    for (int i = 0; i < 4; ++i)
#pragma unroll
        for (int j = 0; j < 4; ++j)
#pragma unroll
            for (int r = 0; r < 4; ++r) acc[i][j][r] = 0.f;

    auto stage = [&](int buf, int k0) {
#pragma unroll
        for (int c = 0; c < 2; ++c) {
            const int chunk = w * 2 + c;
            const int row = chunk * 16 + srow;
            load_lds_16B(A + (size_t)(m0 + row) * K + k0 + sksw,
                         &As[buf][chunk * 512]);
            load_lds_16B(Bt + (size_t)(n0 + row) * K + k0 + sksw,
                         &Bs[buf][chunk * 512]);
        }
    };

    stage(0, 0);
    int cb = 0;
    for (int k0 = 0; k0 < K; k0 += 32) {
        if (k0 + 32 < K) {
            const int nb_ = (cb == 2) ? 0 : cb + 1;
            stage(nb_, k0 + 32);
            asm volatile("s_waitcnt vmcnt(4)" ::: "memory");
        } else {
            asm volatile("s_waitcnt vmcnt(0)" ::: "memory");
        }
        __builtin_amdgcn_s_barrier();          // tile cb landed (all waves)
        __builtin_amdgcn_sched_barrier(0);

        short8 af[4], bfr[4];
#pragma unroll
        for (int mi = 0; mi < 4; ++mi)
            af[mi] = *reinterpret_cast<const short8*>(
                &As[cb][(mb + mi * 16 + l16) * 32 + ((quad ^ rsw) * 8)]);
#pragma unroll
        for (int ni = 0; ni < 4; ++ni)
            bfr[ni] = *reinterpret_cast<const short8*>(
                &Bs[cb][(nbw + ni * 16 + l16) * 32 + ((quad ^ rsw) * 8)]);
        __builtin_amdgcn_s_setprio(1);
#pragma unroll
        for (int mi = 0; mi < 4; ++mi)
#pragma unroll
            for (int ni = 0; ni < 4; ++ni)
                acc[mi][ni] = __builtin_amdgcn_mfma_f32_16x16x32_bf16(
                    af[mi], bfr[ni], acc[mi][ni], 0, 0, 0);
        __builtin_amdgcn_s_setprio(0);

        cb = (cb == 2) ? 0 : cb + 1;
    }

#pragma unroll
    for (int mi = 0; mi < 4; ++mi) {
#pragma unroll
        for (int ni = 0; ni < 4; ++ni) {
            const int col = n0 + nbw + ni * 16 + l16;
            const float bsv = bias[col];
#pragma unroll
            for (int r = 0; r < 4; ++r) {
                const int row = m0 + mb + mi * 16 + quad * 4 + r;
                const float v = acc[mi][ni][r] + bsv;
                if (EPI == 0) {
                    const int seg = col >> 10;  // 0=q 1=k 2=v
                    const int c = col & 1023;
                    if (seg == 0) {
                        qws[(size_t)row * 1024 + c] = __float2bfloat16(v);
                    } else {
                        const int bq = row >> 10, s = row & 1023;
                        const int hh = c >> 6, d = c & 63;
                        const size_t idx =
                            ((size_t)((bq * 16 + hh) * 1024 + s)) * 64 + d;
                        const int kt = s >> 6, key = s & 63;
                        const size_t tbase =
                            ((size_t)((bq * 16 + hh) * 16 + kt)) * 4096;
                        if (seg == 1) {
                            present[idx] = v;
                            // k_ws: [key][d], 16B-chunk swizzle seg^=key&7
                            kws[tbase + key * 64 +
                                ((((d >> 3) ^ (key & 7)) << 3) | (d & 7))] =
                                __float2bfloat16(v);
                        } else {
                            present[HEAD_ELEMS + idx] = v;
                            // vt_ws: [d][key], 16B-chunk swizzle seg^=d&7
                            vtws[tbase + d * 64 +
                                ((((key >> 3) ^ (d & 7)) << 3) | (key & 7))] =
                                __float2bfloat16(v);
                        }
                    }
                } else {
                    outf[(size_t)row * N + col] = v;
                }
            }
        }
    }
}

// ---------------------------------------------------------------------------
// Causal flash attention v5.
//  - 1024 blocks, ONE q-tile each, heavy-first (qt = 15 - idx) so short
//    blocks backfill as slots free up.
//  - XCD-bijective swizzle groups 8 heads per XCD (K/V 1 MB -> L2-resident).
//  - 2 LDS buffers (41 KB -> 3 blocks/CU, +50% waves): stage for tile kt+1
//    is issued AFTER the iteration barrier, so the buffer being overwritten
//    (read during iteration kt-1) is provably quiescent. One barrier/iter.
//  - exp2-domain online softmax, setprio around MFMA clusters.
// ---------------------------------------------------------------------------
__global__ __launch_bounds__(256) void attn_v5(
    const __hip_bfloat16* __restrict__ q_ws,
    const __hip_bfloat16* __restrict__ k_ws,
    const __hip_bfloat16* __restrict__ vt_ws,
    __hip_bfloat16* __restrict__ a_ws)
{
    const int wg  = blockIdx.x;
    const int swz = (wg & 7) * 128 + (wg >> 3);   // 1024 blocks, bijective
    const int qt  = 15 - (swz & 15);              // heavy tiles first
    const int bh  = swz >> 4;                     // 8 consecutive heads/XCD
    const int b = bh >> 4, h = bh & 15;

    const int tid  = threadIdx.x;
    const int wave = tid >> 6, lane = tid & 63;
    const int quad = lane >> 4, l16 = lane & 15;
    const int stripe = wave * 16;                 // wave's 16 q-rows

    const __hip_bfloat16* Kbase = k_ws  + (size_t)bh * 65536;
    const __hip_bfloat16* Vbase = vt_ws + (size_t)bh * 65536;

    __shared__ __align__(16) __hip_bfloat16 Ksf[2][4096];   // [key][d] swz
    __shared__ __align__(16) __hip_bfloat16 Vsf[2][4096];   // [d][key] swz
    __shared__ __align__(16) __hip_bfloat16 Ps[64][72];     // [q][key]

    constexpr float SCL = 0.18033688011f;   // 0.125 * log2(e)

    // Q fragments in registers: rows stripe+l16, k = quad*8 (+32)
    const __hip_bfloat16* Qb =
        q_ws + ((size_t)(b * Ssz + qt * 64 + stripe + l16)) * NXc + h * 64;
    const short8 qf0 = *reinterpret_cast<const short8*>(Qb + quad * 8);
    const short8 qf1 = *reinterpret_cast<const short8*>(Qb + 32 + quad * 8);

    float m_i[4], l_i[4];
#pragma unroll
    for (int r = 0; r < 4; ++r) { m_i[r] = -1e9f; l_i[r] = 0.f; }
    floatx4 oacc[4];
#pragma unroll
    for (int ni = 0; ni < 4; ++ni)
#pragma unroll
        for (int r = 0; r < 4; ++r) oacc[ni][r] = 0.f;

    // ---- prologue: stage tile 0 into buffer 0 ----
#pragma unroll
    for (int c2 = 0; c2 < 2; ++c2) {
        const int c = wave + c2 * 4;
        load_lds_16B(Kbase + c * 512 + (lane << 3), &Ksf[0][c * 512]);
        load_lds_16B(Vbase + c * 512 + (lane << 3), &Vsf[0][c * 512]);
    }

    int cw = 0;
    for (int kt = 0; kt <= qt; ++kt) {
        // my 4 loads for tile kt landed; barrier proves (a) everyone's tile-kt
        // chunks landed, (b) everyone finished computing tile kt-1 (buffer
        // cw^1) -> safe to overwrite it after the barrier.
        asm volatile("s_waitcnt vmcnt(0)" ::: "memory");
        __builtin_amdgcn_s_barrier();
        __builtin_amdgcn_sched_barrier(0);

        if (kt < qt) {
            const __hip_bfloat16* Kt = Kbase + (size_t)(kt + 1) * 4096;
            const __hip_bfloat16* Vt = Vbase + (size_t)(kt + 1) * 4096;
            const int nb_ = cw ^ 1;
#pragma unroll
            for (int c2 = 0; c2 < 2; ++c2) {
                const int c = wave + c2 * 4;
                load_lds_16B(Kt + c * 512 + (lane << 3), &Ksf[nb_][c * 512]);
                load_lds_16B(Vt + c * 512 + (lane << 3), &Vsf[nb_][c * 512]);
            }
        }

        // ---- S = Q K^T : wave's 16 rows x 64 keys ----
        floatx4 sacc[4];
#pragma unroll
        for (int ni = 0; ni < 4; ++ni)
#pragma unroll
            for (int r = 0; r < 4; ++r) sacc[ni][r] = 0.f;
        __builtin_amdgcn_s_setprio(1);
#pragma unroll
        for (int ni = 0; ni < 4; ++ni) {
            const int key = ni * 16 + l16;
            const int sw = key & 7;
            const short8 kf0 = *reinterpret_cast<const short8*>(
                &Ksf[cw][key * 64 + ((quad ^ sw) << 3)]);
            const short8 kf1 = *reinterpret_cast<const short8*>(
                &Ksf[cw][key * 64 + (((4 + quad) ^ sw) << 3)]);
            sacc[ni] = __builtin_amdgcn_mfma_f32_16x16x32_bf16(
                qf0, kf0, sacc[ni], 0, 0, 0);
            sacc[ni] = __builtin_amdgcn_mfma_f32_16x16x32_bf16(
                qf1, kf1, sacc[ni], 0, 0, 0);
        }
        __builtin_amdgcn_s_setprio(0);

        // ---- in-register online softmax, log2 domain ----
        const bool diag = (kt == qt);
        float alpha_[4];
#pragma unroll
        for (int r = 0; r < 4; ++r) {
            const int lrow = stripe + quad * 4 + r;
            float sv[4];
            float mx = -1e30f;
#pragma unroll
            for (int ni = 0; ni < 4; ++ni) {
                float v = sacc[ni][r] * SCL;        // includes log2(e)
                if (diag && (ni * 16 + l16) > lrow) v = -1e9f;
                sv[ni] = v;
                mx = fmaxf(mx, v);
            }
            mx = fmaxf(mx, __shfl_xor(mx, 1));
            mx = fmaxf(mx, __shfl_xor(mx, 2));
            mx = fmaxf(mx, __shfl_xor(mx, 4));
            mx = fmaxf(mx, __shfl_xor(mx, 8));
            const float mnew = fmaxf(m_i[r], mx);
            const float al = exp2f(m_i[r] - mnew);
            m_i[r] = mnew;
            float s = 0.f;
#pragma unroll
            for (int nn = 0; nn < 4; ++nn) {
                const int ni = (nn + quad) & 3;     // bank-rotated stores
                const float p = exp2f(sv[ni] - mnew);
                s += p;
                Ps[lrow][ni * 16 + l16] = __float2bfloat16(p);
            }
            s += __shfl_xor(s, 1);
            s += __shfl_xor(s, 2);
            s += __shfl_xor(s, 4);
            s += __shfl_xor(s, 8);
            l_i[r] = l_i[r] * al + s;
            alpha_[r] = al;
        }

        // rescale O (registers only)
#pragma unroll
        for (int ni = 0; ni < 4; ++ni)
#pragma unroll
            for (int r = 0; r < 4; ++r) oacc[ni][r] *= alpha_[r];

        // ---- O += P V : Ps rows written+read by this wave ----
        __builtin_amdgcn_s_setprio(1);
#pragma unroll
        for (int kk = 0; kk < 64; kk += 32) {
            const short8 pf = *reinterpret_cast<const short8*>(
                &Ps[stripe + l16][kk + quad * 8]);
#pragma unroll
            for (int ni = 0; ni < 4; ++ni) {
                const int d = ni * 16 + l16;
                const int chunk = (kk >> 3) + quad;
                const short8 vf = *reinterpret_cast<const short8*>(
                    &Vsf[cw][d * 64 + ((chunk ^ (d & 7)) << 3)]);
                oacc[ni] = __builtin_amdgcn_mfma_f32_16x16x32_bf16(
                    pf, vf, oacc[ni], 0, 0, 0);
            }
        }
        __builtin_amdgcn_s_setprio(0);

        cw ^= 1;
    }

    // ---- epilogue: O / l -> a_ws ----
#pragma unroll
    for (int ni = 0; ni < 4; ++ni) {
#pragma unroll
        for (int r = 0; r < 4; ++r) {
            const int row = qt * 64 + stripe + quad * 4 + r;
            const int col = h * 64 + ni * 16 + l16;
            const float inv = 1.0f / fmaxf(l_i[r], 1e-20f);
            a_ws[((size_t)(b * Ssz + row)) * NXc + col] =
                __float2bfloat16(oacc[ni][r] * inv);
        }
    }
}

// ===========================================================================
// FALLBACK PATH (round-3, known-passing; used if ws_size < 32 MB)
// ===========================================================================
template <int EPI>
__global__ __launch_bounds__(256) void gemm64(
    const void* __restrict__ Av, const float* __restrict__ Bw,
    const float* __restrict__ bias, float* __restrict__ out0,
    float* __restrict__ present, int M, int N, int K)
{
    __shared__ __align__(16) __hip_bfloat16 As[64][40];
    __shared__ __align__(16) __hip_bfloat16 Bs[64][40];
    const int tid = threadIdx.x;
    const int wave = tid >> 6, lane = tid & 63;
    const int quad = lane >> 4, l16 = lane & 15;
    const int m0 = blockIdx.y * 64, n0 = blockIdx.x * 64;
    const int mb = (wave >> 1) * 32, nb = (wave & 1) * 32;
    const int arow = tid >> 2, aseg = tid & 3;
    const int brow = tid >> 3, bseg = tid & 7;
    floatx4 acc[2][2];
#pragma unroll
    for (int i = 0; i < 2; ++i)
#pragma unroll
        for (int j = 0; j < 2; ++j)
#pragma unroll
            for (int r = 0; r < 4; ++r) acc[i][j][r] = 0.f;
    for (int k0 = 0; k0 < K; k0 += 32) {
        if (EPI == 0) {
            const float* A = (const float*)Av;
            *reinterpret_cast<uint4*>(&As[arow][aseg * 8]) =
                cvt8(A + (size_t)(m0 + arow) * K + k0 + aseg * 8);
        } else {
            const __hip_bfloat16* A = (const __hip_bfloat16*)Av;
            *reinterpret_cast<uint4*>(&As[arow][aseg * 8]) =
                *reinterpret_cast<const uint4*>(
                    A + (size_t)(m0 + arow) * K + k0 + aseg * 8);
        }
        const float* bp = Bw + (size_t)(k0 + brow) * N + n0 + bseg * 8;
        float4 b0 = *reinterpret_cast<const float4*>(bp);
        float4 b1 = *reinterpret_cast<const float4*>(bp + 4);
        Bs[bseg * 8 + 0][brow] = __float2bfloat16(b0.x);
        Bs[bseg * 8 + 1][brow] = __float2bfloat16(b0.y);
        Bs[bseg * 8 + 2][brow] = __float2bfloat16(b0.z);
        Bs[bseg * 8 + 3][brow] = __float2bfloat16(b0.w);
        Bs[bseg * 8 + 4][brow] = __float2bfloat16(b1.x);
        Bs[bseg * 8 + 5][brow] = __float2bfloat16(b1.y);
        Bs[bseg * 8 + 6][brow] = __float2bfloat16(b1.z);
        Bs[bseg * 8 + 7][brow] = __float2bfloat16(b1.w);
        __syncthreads();
        short8 af[2], bf[2];
#pragma unroll
        for (int mm = 0; mm < 2; ++mm)
            af[mm] = *reinterpret_cast<const short8*>(&As[mb + mm * 16 + l16][quad * 8]);
#pragma unroll
        for (int nn = 0; nn < 2; ++nn)
            bf[nn] = *reinterpret_cast<const short8*>(&Bs[nb + nn * 16 + l16][quad * 8]);
#pragma unroll
        for (int mm = 0; mm < 2; ++mm)
#pragma unroll
            for (int nn = 0; nn < 2; ++nn)
                acc[mm][nn] = __builtin_amdgcn_mfma_f32_16x16x32_bf16(
                    af[mm], bf[nn], acc[mm][nn], 0, 0, 0);
        __syncthreads();
    }
#pragma unroll
    for (int mm = 0; mm < 2; ++mm)
#pragma unroll
        for (int nn = 0; nn < 2; ++nn) {
            const int col = n0 + nb + nn * 16 + l16;
            const float bsv = bias[col];
#pragma unroll
            for (int r = 0; r < 4; ++r) {
                const int row = m0 + mb + mm * 16 + quad * 4 + r;
                const float v = acc[mm][nn][r] + bsv;
                if (EPI == 0) {
                    const int seg = col >> 10;
                    const int c = col & 1023;
                    if (seg == 0) out0[(size_t)row * 1024 + c] = v;
                    else {
                        const int b = row >> 10, s = row & 1023;
                        const int h = c >> 6, d = c & 63;
                        const size_t idx = ((size_t)((b * 16 + h) * 1024 + s)) * 64 + d;
                        if (seg == 1) present[idx] = v;
                        else          present[HEAD_ELEMS + idx] = v;
                    }
                } else out0[(size_t)row * N + col] = v;
            }
        }
}

__global__ __launch_bounds__(256) void attn64(
    const float* __restrict__ qbuf, const float* __restrict__ present,
    __hip_bfloat16* __restrict__ a_ws)
{
    const int qt = blockIdx.x, h = blockIdx.y, b = blockIdx.z;
    const int tid = threadIdx.x;
    const int wave = tid >> 6, lane = tid & 63;
    const int quad = lane >> 4, l16 = lane & 15;
    const int mb = (wave >> 1) * 32, nb = (wave & 1) * 32;
    const size_t headoff = ((size_t)(b * 16 + h)) * Ssz * HDc;
    const float* Qb = qbuf + ((size_t)(b * Ssz + qt * 64)) * NXc + h * 64;
    const float* Kp = present + headoff;
    const float* Vp = present + HEAD_ELEMS + headoff;
    __shared__ __align__(16) __hip_bfloat16 Qs[64][72];
    __shared__ __align__(16) __hip_bfloat16 Ks[64][72];
    __shared__ __align__(16) __hip_bfloat16 Vts[64][72];
    __shared__ __align__(16) __hip_bfloat16 Ps[64][72];
    __shared__ float Sc[64][65];
    __shared__ float mrow[64], lrow[64], arw[64];
#pragma unroll
    for (int it = 0; it < 2; ++it) {
        const int c = tid + it * 256;
        const int row = c >> 3, seg = c & 7;
        *reinterpret_cast<uint4*>(&Qs[row][seg * 8]) =
            cvt8(Qb + (size_t)row * NXc + seg * 8);
    }
    if (tid < 64) { mrow[tid] = -1e9f; lrow[tid] = 0.f; }
    floatx4 oacc[2][2];
#pragma unroll
    for (int i = 0; i < 2; ++i)
#pragma unroll
        for (int j = 0; j < 2; ++j)
#pragma unroll
            for (int r = 0; r < 4; ++r) oacc[i][j][r] = 0.f;
    __syncthreads();
    for (int kt = 0; kt <= qt; ++kt) {
#pragma unroll
        for (int it = 0; it < 2; ++it) {
            const int c = tid + it * 256;
            const int row = c >> 3, seg = c & 7;
            *reinterpret_cast<uint4*>(&Ks[row][seg * 8]) =
                cvt8(Kp + (size_t)(kt * 64 + row) * 64 + seg * 8);
            const float* vp = Vp + (size_t)(kt * 64 + row) * 64 + seg * 8;
            float4 v0 = *reinterpret_cast<const float4*>(vp);
            float4 v1 = *reinterpret_cast<const float4*>(vp + 4);
            Vts[seg * 8 + 0][row] = __float2bfloat16(v0.x);
            Vts[seg * 8 + 1][row] = __float2bfloat16(v0.y);
            Vts[seg * 8 + 2][row] = __float2bfloat16(v0.z);
            Vts[seg * 8 + 3][row] = __float2bfloat16(v0.w);
            Vts[seg * 8 + 4][row] = __float2bfloat16(v1.x);
            Vts[seg * 8 + 5][row] = __float2bfloat16(v1.y);
            Vts[seg * 8 + 6][row] = __float2bfloat16(v1.z);
            Vts[seg * 8 + 7][row] = __float2bfloat16(v1.w);
        }
        __syncthreads();
        floatx4 sacc[2][2];
#pragma unroll
        for (int i = 0; i < 2; ++i)
#pragma unroll
            for (int j = 0; j < 2; ++j)
#pragma unroll
                for (int r = 0; r < 4; ++r) sacc[i][j][r] = 0.f;
#pragma unroll
        for (int kd = 0; kd < 64; kd += 32) {
            short8 af[2], bf[2];
#pragma unroll
            for (int mm = 0; mm < 2; ++mm)
                af[mm] = *reinterpret_cast<const short8*>(&Qs[mb + mm * 16 + l16][kd + quad * 8]);
#pragma unroll
            for (int nn = 0; nn < 2; ++nn)
                bf[nn] = *reinterpret_cast<const short8*>(&Ks[nb + nn * 16 + l16][kd + quad * 8]);
#pragma unroll
            for (int mm = 0; mm < 2; ++mm)
#pragma unroll
                for (int nn = 0; nn < 2; ++nn)
                    sacc[mm][nn] = __builtin_amdgcn_mfma_f32_16x16x32_bf16(
                        af[mm], bf[nn], sacc[mm][nn], 0, 0, 0);
        }
        const bool diag = (kt == qt);
#pragma unroll
        for (int mm = 0; mm < 2; ++mm)
#pragma unroll
            for (int nn = 0; nn < 2; ++nn)
#pragma unroll
                for (int r = 0; r < 4; ++r) {
                    const int row = mb + mm * 16 + quad * 4 + r;
                    const int col = nb + nn * 16 + l16;
                    float v = fminf(fmaxf(sacc[mm][nn][r] * 0.125f, -1e8f), 1e8f);
                    if (diag && col > row) v = -1e9f;
                    Sc[row][col] = v;
                }
        __syncthreads();
        if (tid < 64) {
            const int r = tid;
            const float mo = mrow[r];
            float mx = mo;
            for (int c = 0; c < 64; ++c) mx = fmaxf(mx, Sc[r][c]);
            const float al = (mo <= -5e8f) ? 0.f : __expf(mo - mx);
            float sum = 0.f;
            for (int c = 0; c < 64; ++c) {
                const float sv = Sc[r][c];
                const float p = (sv <= -5e8f) ? 0.f : __expf(sv - mx);
                sum += p;
                Ps[r][c] = __float2bfloat16(p);
            }
            mrow[r] = mx;
            lrow[r] = lrow[r] * al + sum;
            arw[r]  = al;
        }
        __syncthreads();
#pragma unroll
        for (int mm = 0; mm < 2; ++mm) {
            const int rbase = mb + mm * 16 + quad * 4;
#pragma unroll
            for (int r = 0; r < 4; ++r) {
                const float al = arw[rbase + r];
                oacc[mm][0][r] *= al;
                oacc[mm][1][r] *= al;
            }
        }
#pragma unroll
        for (int kk = 0; kk < 64; kk += 32) {
            short8 pf[2], vf[2];
#pragma unroll
            for (int mm = 0; mm < 2; ++mm)
                pf[mm] = *reinterpret_cast<const short8*>(&Ps[mb + mm * 16 + l16][kk + quad * 8]);
#pragma unroll
            for (int nn = 0; nn < 2; ++nn)
                vf[nn] = *reinterpret_cast<const short8*>(&Vts[nb + nn * 16 + l16][kk + quad * 8]);
#pragma unroll
            for (int mm = 0; mm < 2; ++mm)
#pragma unroll
                for (int nn = 0; nn < 2; ++nn)
                    oacc[mm][nn] = __builtin_amdgcn_mfma_f32_16x16x32_bf16(
                        pf[mm], vf[nn], oacc[mm][nn], 0, 0, 0);
        }
        __syncthreads();
    }
#pragma unroll
    for (int mm = 0; mm < 2; ++mm)
#pragma unroll
        for (int nn = 0; nn < 2; ++nn)
#pragma unroll
            for (int r = 0; r < 4; ++r) {
                const int row = mb + mm * 16 + quad * 4 + r;
                const int col = nb + nn * 16 + l16;
                const float inv = 1.0f / fmaxf(lrow[row], 1e-20f);
                a_ws[((size_t)(b * Ssz + qt * 64 + row)) * NXc + h * 64 + col] =
                    __float2bfloat16(oacc[mm][nn][r] * inv);
            }
}

// ===========================================================================
extern "C" void kernel_launch(void* const* d_in, const int* in_sizes, int n_in,
                              void* d_out, int out_size, void* d_ws, size_t ws_size,
                              hipStream_t stream) {
    const float* x      = (const float*)d_in[0];
    const float* w_attn = (const float*)d_in[1];
    const float* b_attn = (const float*)d_in[2];
    const float* w_proj = (const float*)d_in[3];
    const float* b_proj = (const float*)d_in[4];

    float* out     = (float*)d_out;
    float* present = out + OUT_ELEMS;

    const size_t NEED = 32u * 1024u * 1024u;
    if (ws_size >= NEED) {
        // ws layout (bf16 elems):
        //   reg1 [0,4M)   : x_bf (dead after gemm128p<0>)
        //   reg2 [4M,8M)  : q_ws, then a_ws in-place (attn writes over q)
        //   reg3 [8M,12M) : unused
        //   wTa  [12M,15M): transposed w_attn
        //   wTp  [15M,16M): transposed w_proj
        // k_ws/vt_ws (8 MB each, bf16) live in the `out` region of d_out:
        // written by gemm128p<0>'s epilogue, read by attn_v5, dead before
        // gemm128p<1> overwrites out at the end.
        __hip_bfloat16* reg1 = (__hip_bfloat16*)d_ws;
        __hip_bfloat16* reg2 = reg1 + 4194304;
        __hip_bfloat16* reg3 = reg2 + 4194304;
        __hip_bfloat16* wTa  = reg3 + 4194304;
        __hip_bfloat16* wTp  = wTa + 3145728;
        __hip_bfloat16* kws  = (__hip_bfloat16*)out;
        __hip_bfloat16* vtws = kws + 4194304;

        prep_kernel<<<3072, 256, 0, stream>>>(x, reg1, w_attn, wTa, w_proj, wTp);

        gemm128p<0><<<768, 256, 0, stream>>>(
            reg1, wTa, b_attn, nullptr, reg2, present, kws, vtws,
            4096, 3072, 1024);

        attn_v5<<<1024, 256, 0, stream>>>(reg2, kws, vtws, reg2);

        gemm128p<1><<<256, 256, 0, stream>>>(
            reg2, wTp, b_proj, out, nullptr, nullptr, nullptr, nullptr,
            4096, 1024, 1024);
    } else {
        // round-3 fallback (needs 8 MB ws)
        __hip_bfloat16* a_ws = (__hip_bfloat16*)d_ws;
        hipMemsetAsync(d_ws, 0, (size_t)OUT_ELEMS * sizeof(__hip_bfloat16), stream);
        gemm64<0><<<dim3(48, 64), 256, 0, stream>>>(x, w_attn, b_attn, out, present,
                                                    4096, 3072, 1024);
        attn64<<<dim3(16, 16, 4), 256, 0, stream>>>(out, present, a_ws);
        gemm64<1><<<dim3(16, 64), 256, 0, stream>>>(a_ws, w_proj, b_proj, out, nullptr,
                                                    4096, 1024, 1024);
    }
}

// Round 6
// 197.383 us; speedup vs baseline: 1.0829x; 1.0829x over previous
//
#include <hip/hip_runtime.h>
#include <hip/hip_bf16.h>

typedef __attribute__((ext_vector_type(8))) short short8;
typedef __attribute__((ext_vector_type(4))) float floatx4;

constexpr int Bsz = 4, Ssz = 1024, NXc = 1024, NHc = 16, HDc = 64;
constexpr int OUT_ELEMS  = Bsz * Ssz * NXc;        // 4194304
constexpr int HEAD_ELEMS = Bsz * NHc * Ssz * HDc;  // 4194304

union BF8 { __hip_bfloat16 h[8]; uint4 v; short8 s; };

__device__ __forceinline__ uint4 cvt8(const float* __restrict__ p) {
    float4 a = *reinterpret_cast<const float4*>(p);
    float4 b = *reinterpret_cast<const float4*>(p + 4);
    BF8 u;
    u.h[0] = __float2bfloat16(a.x); u.h[1] = __float2bfloat16(a.y);
    u.h[2] = __float2bfloat16(a.z); u.h[3] = __float2bfloat16(a.w);
    u.h[4] = __float2bfloat16(b.x); u.h[5] = __float2bfloat16(b.y);
    u.h[6] = __float2bfloat16(b.z); u.h[7] = __float2bfloat16(b.w);
    return u.v;
}

// async 16B global -> LDS (wave-uniform LDS base + lane*16)
__device__ __forceinline__ void load_lds_16B(const void* g, void* l) {
    __builtin_amdgcn_global_load_lds(
        (const __attribute__((address_space(1))) unsigned int*)g,
        (__attribute__((address_space(3))) unsigned int*)l, 16, 0, 0);
}

// ===========================================================================
// FAST PATH
// ===========================================================================

// Fused prep: x fp32->bf16 (blocks 0..2047), w_attn transpose (2048..2815),
// w_proj transpose (2816..3071).
__global__ __launch_bounds__(256) void prep_kernel(
    const float* __restrict__ x, __hip_bfloat16* __restrict__ x_bf,
    const float* __restrict__ w_attn, __hip_bfloat16* __restrict__ wTa,
    const float* __restrict__ w_proj, __hip_bfloat16* __restrict__ wTp)
{
    const int bid = blockIdx.x, tid = threadIdx.x;
    __shared__ float t[64][65];
    if (bid < 2048) {
        const int i = (bid * 256 + tid) * 8;   // covers exactly OUT_ELEMS
        *reinterpret_cast<uint4*>(x_bf + i) = cvt8(x + i);
        return;
    }
    const float* in; __hip_bfloat16* outp; int N, bx, by;
    if (bid < 2816) { const int q = bid - 2048; in = w_attn; outp = wTa; N = 3072; bx = q % 48; by = q / 48; }
    else            { const int q = bid - 2816; in = w_proj; outp = wTp; N = 1024; bx = q % 16; by = q / 16; }
    const int k0 = by * 64, n0 = bx * 64;
#pragma unroll
    for (int j = 0; j < 16; ++j) {
        const int idx = tid + j * 256;
        const int row = idx >> 6, col = idx & 63;
        t[row][col] = in[(size_t)(k0 + row) * N + n0 + col];
    }
    __syncthreads();
#pragma unroll
    for (int j = 0; j < 16; ++j) {
        const int idx = tid + j * 256;
        const int orow = idx >> 6, ocol = idx & 63;
        outp[(size_t)(n0 + orow) * 1024 + k0 + ocol] = __float2bfloat16(t[ocol][orow]);
    }
}

// ---------------------------------------------------------------------------
// 128x128-tile bf16 GEMM, BK=32, 3-buffer counted-vmcnt pipeline, LDS
// chunk-XOR swizzle (0 bank conflicts), setprio around MFMA, XCD-bijective
// block swizzle. (Unchanged from round 5 — measured neutral-to-positive.)
// EPI==0 epilogue also emits bf16 swizzled K/V tiles for attention.
// ---------------------------------------------------------------------------
template <int EPI>
__global__ __launch_bounds__(256) void gemm128p(
    const __hip_bfloat16* __restrict__ A,
    const __hip_bfloat16* __restrict__ Bt,
    const float* __restrict__ bias,
    float* __restrict__ outf,
    __hip_bfloat16* __restrict__ qws,
    float* __restrict__ present,
    __hip_bfloat16* __restrict__ kws,
    __hip_bfloat16* __restrict__ vtws,
    int M, int N, int K)
{
    __shared__ __align__(16) __hip_bfloat16 As[3][4096];
    __shared__ __align__(16) __hip_bfloat16 Bs[3][4096];

    const int nbx = N >> 7;
    const int nwg = (M >> 7) * nbx;
    const int wg  = blockIdx.x;
    const int swz = (wg & 7) * (nwg >> 3) + (wg >> 3);
    const int by  = swz / nbx, bx = swz % nbx;   // by-contiguous per XCD

    const int tid  = threadIdx.x;
    const int w    = tid >> 6, lane = tid & 63;
    const int quad = lane >> 4, l16 = lane & 15;
    const int m0 = by * 128, n0 = bx * 128;
    const int mb = (w >> 1) * 64, nbw = (w & 1) * 64;

    const int srow = lane >> 2;
    const int sksw = (((lane & 3) ^ ((lane >> 3) & 3))) * 8;
    const int rsw = (l16 >> 1) & 3;   // fragment-read swizzle

    floatx4 acc[4][4];
#pragma unroll
    for (int i = 0; i < 4; ++i)
#pragma unroll
        for (int j = 0; j < 4; ++j)
#pragma unroll
            for (int r = 0; r < 4; ++r) acc[i][j][r] = 0.f;

    auto stage = [&](int buf, int k0) {
#pragma unroll
        for (int c = 0; c < 2; ++c) {
            const int chunk = w * 2 + c;
            const int row = chunk * 16 + srow;
            load_lds_16B(A + (size_t)(m0 + row) * K + k0 + sksw,
                         &As[buf][chunk * 512]);
            load_lds_16B(Bt + (size_t)(n0 + row) * K + k0 + sksw,
                         &Bs[buf][chunk * 512]);
        }
    };

    stage(0, 0);
    int cb = 0;
    for (int k0 = 0; k0 < K; k0 += 32) {
        if (k0 + 32 < K) {
            const int nb_ = (cb == 2) ? 0 : cb + 1;
            stage(nb_, k0 + 32);
            asm volatile("s_waitcnt vmcnt(4)" ::: "memory");
        } else {
            asm volatile("s_waitcnt vmcnt(0)" ::: "memory");
        }
        __builtin_amdgcn_s_barrier();          // tile cb landed (all waves)
        __builtin_amdgcn_sched_barrier(0);

        short8 af[4], bfr[4];
#pragma unroll
        for (int mi = 0; mi < 4; ++mi)
            af[mi] = *reinterpret_cast<const short8*>(
                &As[cb][(mb + mi * 16 + l16) * 32 + ((quad ^ rsw) * 8)]);
#pragma unroll
        for (int ni = 0; ni < 4; ++ni)
            bfr[ni] = *reinterpret_cast<const short8*>(
                &Bs[cb][(nbw + ni * 16 + l16) * 32 + ((quad ^ rsw) * 8)]);
        __builtin_amdgcn_s_setprio(1);
#pragma unroll
        for (int mi = 0; mi < 4; ++mi)
#pragma unroll
            for (int ni = 0; ni < 4; ++ni)
                acc[mi][ni] = __builtin_amdgcn_mfma_f32_16x16x32_bf16(
                    af[mi], bfr[ni], acc[mi][ni], 0, 0, 0);
        __builtin_amdgcn_s_setprio(0);

        cb = (cb == 2) ? 0 : cb + 1;
    }

#pragma unroll
    for (int mi = 0; mi < 4; ++mi) {
#pragma unroll
        for (int ni = 0; ni < 4; ++ni) {
            const int col = n0 + nbw + ni * 16 + l16;
            const float bsv = bias[col];
#pragma unroll
            for (int r = 0; r < 4; ++r) {
                const int row = m0 + mb + mi * 16 + quad * 4 + r;
                const float v = acc[mi][ni][r] + bsv;
                if (EPI == 0) {
                    const int seg = col >> 10;  // 0=q 1=k 2=v
                    const int c = col & 1023;
                    if (seg == 0) {
                        qws[(size_t)row * 1024 + c] = __float2bfloat16(v);
                    } else {
                        const int bq = row >> 10, s = row & 1023;
                        const int hh = c >> 6, d = c & 63;
                        const size_t idx =
                            ((size_t)((bq * 16 + hh) * 1024 + s)) * 64 + d;
                        const int kt = s >> 6, key = s & 63;
                        const size_t tbase =
                            ((size_t)((bq * 16 + hh) * 16 + kt)) * 4096;
                        if (seg == 1) {
                            present[idx] = v;
                            // k_ws: [key][d], 16B-chunk swizzle seg^=key&7
                            kws[tbase + key * 64 +
                                ((((d >> 3) ^ (key & 7)) << 3) | (d & 7))] =
                                __float2bfloat16(v);
                        } else {
                            present[HEAD_ELEMS + idx] = v;
                            // vt_ws: [d][key], 16B-chunk swizzle seg^=d&7
                            vtws[tbase + d * 64 +
                                ((((key >> 3) ^ (d & 7)) << 3) | (key & 7))] =
                                __float2bfloat16(v);
                        }
                    }
                } else {
                    outf[(size_t)row * N + col] = v;
                }
            }
        }
    }
}

// ---------------------------------------------------------------------------
// Causal flash attention v6 = v4's proven schedule + depth-2 pipeline +
// XCD head-grouping + exp2 softmax.
//  - 512 blocks, paired q-tiles {8+bx, 7-bx}: uniform 17 iterations, ALL
//    blocks co-resident at 2 blocks/CU from t=0 (no tail).
//  - XCD-bijective swizzle: 8 heads per XCD -> K/V (2 MB) L2-resident.
//  - Depth-2 pipeline, 4 K/V LDS buffers (73 KB): at iter kt issue
//    stage(kt+2), wait vmcnt(8) (tiles kt+1,kt+2 stay in flight), ONE
//    barrier. Buffer (kt+2)&3 was last read at iter kt-2 -> quiescent past
//    the kt-1 barrier -> race-free.
//  - exp2-domain online softmax, setprio around MFMA clusters.
// ---------------------------------------------------------------------------
__global__ __launch_bounds__(256) void attn_v6(
    const __hip_bfloat16* __restrict__ q_ws,
    const __hip_bfloat16* __restrict__ k_ws,
    const __hip_bfloat16* __restrict__ vt_ws,
    __hip_bfloat16* __restrict__ a_ws)
{
    const int wg  = blockIdx.x;
    const int swz = (wg & 7) * 64 + (wg >> 3);    // 512 blocks, bijective
    const int bx  = swz & 7;                      // q-pair index
    const int bh  = swz >> 3;                     // 8 consecutive heads/XCD
    const int b = bh >> 4, h = bh & 15;

    const int tid  = threadIdx.x;
    const int wave = tid >> 6, lane = tid & 63;
    const int quad = lane >> 4, l16 = lane & 15;
    const int stripe = wave * 16;                 // wave's 16 q-rows

    const __hip_bfloat16* Kbase = k_ws  + (size_t)bh * 65536;
    const __hip_bfloat16* Vbase = vt_ws + (size_t)bh * 65536;

    __shared__ __align__(16) __hip_bfloat16 Ksf[4][4096];   // [key][d] swz
    __shared__ __align__(16) __hip_bfloat16 Vsf[4][4096];   // [d][key] swz
    __shared__ __align__(16) __hip_bfloat16 Ps[64][72];     // [q][key]

    constexpr float SCL = 0.18033688011f;   // 0.125 * log2(e)

#pragma unroll
    for (int pass = 0; pass < 2; ++pass) {
        const int qt = (pass == 0) ? (8 + bx) : (7 - bx);

        // Q fragments in registers: rows stripe+l16, k = quad*8 (+32)
        const __hip_bfloat16* Qb =
            q_ws + ((size_t)(b * Ssz + qt * 64 + stripe + l16)) * NXc + h * 64;
        const short8 qf0 = *reinterpret_cast<const short8*>(Qb + quad * 8);
        const short8 qf1 = *reinterpret_cast<const short8*>(Qb + 32 + quad * 8);

        float m_i[4], l_i[4];
#pragma unroll
        for (int r = 0; r < 4; ++r) { m_i[r] = -1e9f; l_i[r] = 0.f; }
        floatx4 oacc[4];
#pragma unroll
        for (int ni = 0; ni < 4; ++ni)
#pragma unroll
            for (int r = 0; r < 4; ++r) oacc[ni][r] = 0.f;

        // ---- prologue: stage tiles 0 and 1 (depth-2) ----
#pragma unroll
        for (int c2 = 0; c2 < 2; ++c2) {
            const int c = wave + c2 * 4;
            load_lds_16B(Kbase + c * 512 + (lane << 3), &Ksf[0][c * 512]);
            load_lds_16B(Vbase + c * 512 + (lane << 3), &Vsf[0][c * 512]);
        }
        if (qt >= 1) {
#pragma unroll
            for (int c2 = 0; c2 < 2; ++c2) {
                const int c = wave + c2 * 4;
                load_lds_16B(Kbase + 4096 + c * 512 + (lane << 3),
                             &Ksf[1][c * 512]);
                load_lds_16B(Vbase + 4096 + c * 512 + (lane << 3),
                             &Vsf[1][c * 512]);
            }
        }

        for (int kt = 0; kt <= qt; ++kt) {
            const int cw = kt & 3;
            // ---- issue tile kt+2's loads; counted wait drains tile kt ----
            if (kt + 2 <= qt) {
                const int nb_ = (kt + 2) & 3;
                const __hip_bfloat16* Kt = Kbase + (size_t)(kt + 2) * 4096;
                const __hip_bfloat16* Vt = Vbase + (size_t)(kt + 2) * 4096;
#pragma unroll
                for (int c2 = 0; c2 < 2; ++c2) {
                    const int c = wave + c2 * 4;
                    load_lds_16B(Kt + c * 512 + (lane << 3), &Ksf[nb_][c * 512]);
                    load_lds_16B(Vt + c * 512 + (lane << 3), &Vsf[nb_][c * 512]);
                }
                asm volatile("s_waitcnt vmcnt(8)" ::: "memory");
            } else if (kt + 1 <= qt) {
                asm volatile("s_waitcnt vmcnt(4)" ::: "memory");
            } else {
                asm volatile("s_waitcnt vmcnt(0)" ::: "memory");
            }
            __builtin_amdgcn_s_barrier();        // all waves: tile kt landed
            __builtin_amdgcn_sched_barrier(0);

            // ---- S = Q K^T : wave's 16 rows x 64 keys ----
            floatx4 sacc[4];
#pragma unroll
            for (int ni = 0; ni < 4; ++ni)
#pragma unroll
                for (int r = 0; r < 4; ++r) sacc[ni][r] = 0.f;
            __builtin_amdgcn_s_setprio(1);
#pragma unroll
            for (int ni = 0; ni < 4; ++ni) {
                const int key = ni * 16 + l16;
                const int sw = key & 7;
                const short8 kf0 = *reinterpret_cast<const short8*>(
                    &Ksf[cw][key * 64 + ((quad ^ sw) << 3)]);
                const short8 kf1 = *reinterpret_cast<const short8*>(
                    &Ksf[cw][key * 64 + (((4 + quad) ^ sw) << 3)]);
                sacc[ni] = __builtin_amdgcn_mfma_f32_16x16x32_bf16(
                    qf0, kf0, sacc[ni], 0, 0, 0);
                sacc[ni] = __builtin_amdgcn_mfma_f32_16x16x32_bf16(
                    qf1, kf1, sacc[ni], 0, 0, 0);
            }
            __builtin_amdgcn_s_setprio(0);

            // ---- in-register online softmax, log2 domain ----
            const bool diag = (kt == qt);
            float alpha_[4];
#pragma unroll
            for (int r = 0; r < 4; ++r) {
                const int lrow = stripe + quad * 4 + r;
                float sv[4];
                float mx = -1e30f;
#pragma unroll
                for (int ni = 0; ni < 4; ++ni) {
                    float v = sacc[ni][r] * SCL;        // includes log2(e)
                    if (diag && (ni * 16 + l16) > lrow) v = -1e9f;
                    sv[ni] = v;
                    mx = fmaxf(mx, v);
                }
                mx = fmaxf(mx, __shfl_xor(mx, 1));
                mx = fmaxf(mx, __shfl_xor(mx, 2));
                mx = fmaxf(mx, __shfl_xor(mx, 4));
                mx = fmaxf(mx, __shfl_xor(mx, 8));
                const float mnew = fmaxf(m_i[r], mx);
                const float al = exp2f(m_i[r] - mnew);
                m_i[r] = mnew;
                float s = 0.f;
#pragma unroll
                for (int nn = 0; nn < 4; ++nn) {
                    const int ni = (nn + quad) & 3;     // bank-rotated stores
                    const float p = exp2f(sv[ni] - mnew);
                    s += p;
                    Ps[lrow][ni * 16 + l16] = __float2bfloat16(p);
                }
                s += __shfl_xor(s, 1);
                s += __shfl_xor(s, 2);
                s += __shfl_xor(s, 4);
                s += __shfl_xor(s, 8);
                l_i[r] = l_i[r] * al + s;
                alpha_[r] = al;
            }

            // rescale O (registers only)
#pragma unroll
            for (int ni = 0; ni < 4; ++ni)
#pragma unroll
                for (int r = 0; r < 4; ++r) oacc[ni][r] *= alpha_[r];

            // ---- O += P V : Ps rows written+read by this wave ----
            __builtin_amdgcn_s_setprio(1);
#pragma unroll
            for (int kk = 0; kk < 64; kk += 32) {
                const short8 pf = *reinterpret_cast<const short8*>(
                    &Ps[stripe + l16][kk + quad * 8]);
#pragma unroll
                for (int ni = 0; ni < 4; ++ni) {
                    const int d = ni * 16 + l16;
                    const int chunk = (kk >> 3) + quad;
                    const short8 vf = *reinterpret_cast<const short8*>(
                        &Vsf[cw][d * 64 + ((chunk ^ (d & 7)) << 3)]);
                    oacc[ni] = __builtin_amdgcn_mfma_f32_16x16x32_bf16(
                        pf, vf, oacc[ni], 0, 0, 0);
                }
            }
            __builtin_amdgcn_s_setprio(0);
        }

        // all waves done reading LDS before next pass's prologue staging
        __builtin_amdgcn_s_barrier();

        // ---- epilogue: O / l -> a_ws ----
#pragma unroll
        for (int ni = 0; ni < 4; ++ni) {
#pragma unroll
            for (int r = 0; r < 4; ++r) {
                const int row = qt * 64 + stripe + quad * 4 + r;
                const int col = h * 64 + ni * 16 + l16;
                const float inv = 1.0f / fmaxf(l_i[r], 1e-20f);
                a_ws[((size_t)(b * Ssz + row)) * NXc + col] =
                    __float2bfloat16(oacc[ni][r] * inv);
            }
        }
    }
}

// ===========================================================================
// FALLBACK PATH (round-3, known-passing; used if ws_size < 32 MB)
// ===========================================================================
template <int EPI>
__global__ __launch_bounds__(256) void gemm64(
    const void* __restrict__ Av, const float* __restrict__ Bw,
    const float* __restrict__ bias, float* __restrict__ out0,
    float* __restrict__ present, int M, int N, int K)
{
    __shared__ __align__(16) __hip_bfloat16 As[64][40];
    __shared__ __align__(16) __hip_bfloat16 Bs[64][40];
    const int tid = threadIdx.x;
    const int wave = tid >> 6, lane = tid & 63;
    const int quad = lane >> 4, l16 = lane & 15;
    const int m0 = blockIdx.y * 64, n0 = blockIdx.x * 64;
    const int mb = (wave >> 1) * 32, nb = (wave & 1) * 32;
    const int arow = tid >> 2, aseg = tid & 3;
    const int brow = tid >> 3, bseg = tid & 7;
    floatx4 acc[2][2];
#pragma unroll
    for (int i = 0; i < 2; ++i)
#pragma unroll
        for (int j = 0; j < 2; ++j)
#pragma unroll
            for (int r = 0; r < 4; ++r) acc[i][j][r] = 0.f;
    for (int k0 = 0; k0 < K; k0 += 32) {
        if (EPI == 0) {
            const float* A = (const float*)Av;
            *reinterpret_cast<uint4*>(&As[arow][aseg * 8]) =
                cvt8(A + (size_t)(m0 + arow) * K + k0 + aseg * 8);
        } else {
            const __hip_bfloat16* A = (const __hip_bfloat16*)Av;
            *reinterpret_cast<uint4*>(&As[arow][aseg * 8]) =
                *reinterpret_cast<const uint4*>(
                    A + (size_t)(m0 + arow) * K + k0 + aseg * 8);
        }
        const float* bp = Bw + (size_t)(k0 + brow) * N + n0 + bseg * 8;
        float4 b0 = *reinterpret_cast<const float4*>(bp);
        float4 b1 = *reinterpret_cast<const float4*>(bp + 4);
        Bs[bseg * 8 + 0][brow] = __float2bfloat16(b0.x);
        Bs[bseg * 8 + 1][brow] = __float2bfloat16(b0.y);
        Bs[bseg * 8 + 2][brow] = __float2bfloat16(b0.z);
        Bs[bseg * 8 + 3][brow] = __float2bfloat16(b0.w);
        Bs[bseg * 8 + 4][brow] = __float2bfloat16(b1.x);
        Bs[bseg * 8 + 5][brow] = __float2bfloat16(b1.y);
        Bs[bseg * 8 + 6][brow] = __float2bfloat16(b1.z);
        Bs[bseg * 8 + 7][brow] = __float2bfloat16(b1.w);
        __syncthreads();
        short8 af[2], bf[2];
#pragma unroll
        for (int mm = 0; mm < 2; ++mm)
            af[mm] = *reinterpret_cast<const short8*>(&As[mb + mm * 16 + l16][quad * 8]);
#pragma unroll
        for (int nn = 0; nn < 2; ++nn)
            bf[nn] = *reinterpret_cast<const short8*>(&Bs[nb + nn * 16 + l16][quad * 8]);
#pragma unroll
        for (int mm = 0; mm < 2; ++mm)
#pragma unroll
            for (int nn = 0; nn < 2; ++nn)
                acc[mm][nn] = __builtin_amdgcn_mfma_f32_16x16x32_bf16(
                    af[mm], bf[nn], acc[mm][nn], 0, 0, 0);
        __syncthreads();
    }
#pragma unroll
    for (int mm = 0; mm < 2; ++mm)
#pragma unroll
        for (int nn = 0; nn < 2; ++nn) {
            const int col = n0 + nb + nn * 16 + l16;
            const float bsv = bias[col];
#pragma unroll
            for (int r = 0; r < 4; ++r) {
                const int row = m0 + mb + mm * 16 + quad * 4 + r;
                const float v = acc[mm][nn][r] + bsv;
                if (EPI == 0) {
                    const int seg = col >> 10;
                    const int c = col & 1023;
                    if (seg == 0) out0[(size_t)row * 1024 + c] = v;
                    else {
                        const int b = row >> 10, s = row & 1023;
                        const int h = c >> 6, d = c & 63;
                        const size_t idx = ((size_t)((b * 16 + h) * 1024 + s)) * 64 + d;
                        if (seg == 1) present[idx] = v;
                        else          present[HEAD_ELEMS + idx] = v;
                    }
                } else out0[(size_t)row * N + col] = v;
            }
        }
}

__global__ __launch_bounds__(256) void attn64(
    const float* __restrict__ qbuf, const float* __restrict__ present,
    __hip_bfloat16* __restrict__ a_ws)
{
    const int qt = blockIdx.x, h = blockIdx.y, b = blockIdx.z;
    const int tid = threadIdx.x;
    const int wave = tid >> 6, lane = tid & 63;
    const int quad = lane >> 4, l16 = lane & 15;
    const int mb = (wave >> 1) * 32, nb = (wave & 1) * 32;
    const size_t headoff = ((size_t)(b * 16 + h)) * Ssz * HDc;
    const float* Qb = qbuf + ((size_t)(b * Ssz + qt * 64)) * NXc + h * 64;
    const float* Kp = present + headoff;
    const float* Vp = present + HEAD_ELEMS + headoff;
    __shared__ __align__(16) __hip_bfloat16 Qs[64][72];
    __shared__ __align__(16) __hip_bfloat16 Ks[64][72];
    __shared__ __align__(16) __hip_bfloat16 Vts[64][72];
    __shared__ __align__(16) __hip_bfloat16 Ps[64][72];
    __shared__ float Sc[64][65];
    __shared__ float mrow[64], lrow[64], arw[64];
#pragma unroll
    for (int it = 0; it < 2; ++it) {
        const int c = tid + it * 256;
        const int row = c >> 3, seg = c & 7;
        *reinterpret_cast<uint4*>(&Qs[row][seg * 8]) =
            cvt8(Qb + (size_t)row * NXc + seg * 8);
    }
    if (tid < 64) { mrow[tid] = -1e9f; lrow[tid] = 0.f; }
    floatx4 oacc[2][2];
#pragma unroll
    for (int i = 0; i < 2; ++i)
#pragma unroll
        for (int j = 0; j < 2; ++j)
#pragma unroll
            for (int r = 0; r < 4; ++r) oacc[i][j][r] = 0.f;
    __syncthreads();
    for (int kt = 0; kt <= qt; ++kt) {
#pragma unroll
        for (int it = 0; it < 2; ++it) {
            const int c = tid + it * 256;
            const int row = c >> 3, seg = c & 7;
            *reinterpret_cast<uint4*>(&Ks[row][seg * 8]) =
                cvt8(Kp + (size_t)(kt * 64 + row) * 64 + seg * 8);
            const float* vp = Vp + (size_t)(kt * 64 + row) * 64 + seg * 8;
            float4 v0 = *reinterpret_cast<const float4*>(vp);
            float4 v1 = *reinterpret_cast<const float4*>(vp + 4);
            Vts[seg * 8 + 0][row] = __float2bfloat16(v0.x);
            Vts[seg * 8 + 1][row] = __float2bfloat16(v0.y);
            Vts[seg * 8 + 2][row] = __float2bfloat16(v0.z);
            Vts[seg * 8 + 3][row] = __float2bfloat16(v0.w);
            Vts[seg * 8 + 4][row] = __float2bfloat16(v1.x);
            Vts[seg * 8 + 5][row] = __float2bfloat16(v1.y);
            Vts[seg * 8 + 6][row] = __float2bfloat16(v1.z);
            Vts[seg * 8 + 7][row] = __float2bfloat16(v1.w);
        }
        __syncthreads();
        floatx4 sacc[2][2];
#pragma unroll
        for (int i = 0; i < 2; ++i)
#pragma unroll
            for (int j = 0; j < 2; ++j)
#pragma unroll
                for (int r = 0; r < 4; ++r) sacc[i][j][r] = 0.f;
#pragma unroll
        for (int kd = 0; kd < 64; kd += 32) {
            short8 af[2], bf[2];
#pragma unroll
            for (int mm = 0; mm < 2; ++mm)
                af[mm] = *reinterpret_cast<const short8*>(&Qs[mb + mm * 16 + l16][kd + quad * 8]);
#pragma unroll
            for (int nn = 0; nn < 2; ++nn)
                bf[nn] = *reinterpret_cast<const short8*>(&Ks[nb + nn * 16 + l16][kd + quad * 8]);
#pragma unroll
            for (int mm = 0; mm < 2; ++mm)
#pragma unroll
                for (int nn = 0; nn < 2; ++nn)
                    sacc[mm][nn] = __builtin_amdgcn_mfma_f32_16x16x32_bf16(
                        af[mm], bf[nn], sacc[mm][nn], 0, 0, 0);
        }
        const bool diag = (kt == qt);
#pragma unroll
        for (int mm = 0; mm < 2; ++mm)
#pragma unroll
            for (int nn = 0; nn < 2; ++nn)
#pragma unroll
                for (int r = 0; r < 4; ++r) {
                    const int row = mb + mm * 16 + quad * 4 + r;
                    const int col = nb + nn * 16 + l16;
                    float v = fminf(fmaxf(sacc[mm][nn][r] * 0.125f, -1e8f), 1e8f);
                    if (diag && col > row) v = -1e9f;
                    Sc[row][col] = v;
                }
        __syncthreads();
        if (tid < 64) {
            const int r = tid;
            const float mo = mrow[r];
            float mx = mo;
            for (int c = 0; c < 64; ++c) mx = fmaxf(mx, Sc[r][c]);
            const float al = (mo <= -5e8f) ? 0.f : __expf(mo - mx);
            float sum = 0.f;
            for (int c = 0; c < 64; ++c) {
                const float sv = Sc[r][c];
                const float p = (sv <= -5e8f) ? 0.f : __expf(sv - mx);
                sum += p;
                Ps[r][c] = __float2bfloat16(p);
            }
            mrow[r] = mx;
            lrow[r] = lrow[r] * al + sum;
            arw[r]  = al;
        }
        __syncthreads();
#pragma unroll
        for (int mm = 0; mm < 2; ++mm) {
            const int rbase = mb + mm * 16 + quad * 4;
#pragma unroll
            for (int r = 0; r < 4; ++r) {
                const float al = arw[rbase + r];
                oacc[mm][0][r] *= al;
                oacc[mm][1][r] *= al;
            }
        }
#pragma unroll
        for (int kk = 0; kk < 64; kk += 32) {
            short8 pf[2], vf[2];
#pragma unroll
            for (int mm = 0; mm < 2; ++mm)
                pf[mm] = *reinterpret_cast<const short8*>(&Ps[mb + mm * 16 + l16][kk + quad * 8]);
#pragma unroll
            for (int nn = 0; nn < 2; ++nn)
                vf[nn] = *reinterpret_cast<const short8*>(&Vts[nb + nn * 16 + l16][kk + quad * 8]);
#pragma unroll
            for (int mm = 0; mm < 2; ++mm)
#pragma unroll
                for (int nn = 0; nn < 2; ++nn)
                    oacc[mm][nn] = __builtin_amdgcn_mfma_f32_16x16x32_bf16(
                        pf[mm], vf[nn], oacc[mm][nn], 0, 0, 0);
        }
        __syncthreads();
    }
#pragma unroll
    for (int mm = 0; mm < 2; ++mm)
#pragma unroll
        for (int nn = 0; nn < 2; ++nn)
#pragma unroll
            for (int r = 0; r < 4; ++r) {
                const int row = mb + mm * 16 + quad * 4 + r;
                const int col = nb + nn * 16 + l16;
                const float inv = 1.0f / fmaxf(lrow[row], 1e-20f);
                a_ws[((size_t)(b * Ssz + qt * 64 + row)) * NXc + h * 64 + col] =
                    __float2bfloat16(oacc[mm][nn][r] * inv);
            }
}

// ===========================================================================
extern "C" void kernel_launch(void* const* d_in, const int* in_sizes, int n_in,
                              void* d_out, int out_size, void* d_ws, size_t ws_size,
                              hipStream_t stream) {
    const float* x      = (const float*)d_in[0];
    const float* w_attn = (const float*)d_in[1];
    const float* b_attn = (const float*)d_in[2];
    const float* w_proj = (const float*)d_in[3];
    const float* b_proj = (const float*)d_in[4];

    float* out     = (float*)d_out;
    float* present = out + OUT_ELEMS;

    const size_t NEED = 32u * 1024u * 1024u;
    if (ws_size >= NEED) {
        // ws layout (bf16 elems):
        //   reg1 [0,4M)   : x_bf (dead after gemm128p<0>)
        //   reg2 [4M,8M)  : q_ws, then a_ws in-place (attn writes over q)
        //   reg3 [8M,12M) : unused
        //   wTa  [12M,15M): transposed w_attn
        //   wTp  [15M,16M): transposed w_proj
        // k_ws/vt_ws (8 MB each, bf16) live in the `out` region of d_out:
        // written by gemm128p<0>'s epilogue, read by attn_v6, dead before
        // gemm128p<1> overwrites out at the end.
        __hip_bfloat16* reg1 = (__hip_bfloat16*)d_ws;
        __hip_bfloat16* reg2 = reg1 + 4194304;
        __hip_bfloat16* reg3 = reg2 + 4194304;
        __hip_bfloat16* wTa  = reg3 + 4194304;
        __hip_bfloat16* wTp  = wTa + 3145728;
        __hip_bfloat16* kws  = (__hip_bfloat16*)out;
        __hip_bfloat16* vtws = kws + 4194304;

        prep_kernel<<<3072, 256, 0, stream>>>(x, reg1, w_attn, wTa, w_proj, wTp);

        gemm128p<0><<<768, 256, 0, stream>>>(
            reg1, wTa, b_attn, nullptr, reg2, present, kws, vtws,
            4096, 3072, 1024);

        attn_v6<<<512, 256, 0, stream>>>(reg2, kws, vtws, reg2);

        gemm128p<1><<<256, 256, 0, stream>>>(
            reg2, wTp, b_proj, out, nullptr, nullptr, nullptr, nullptr,
            4096, 1024, 1024);
    } else {
        // round-3 fallback (needs 8 MB ws)
        __hip_bfloat16* a_ws = (__hip_bfloat16*)d_ws;
        hipMemsetAsync(d_ws, 0, (size_t)OUT_ELEMS * sizeof(__hip_bfloat16), stream);
        gemm64<0><<<dim3(48, 64), 256, 0, stream>>>(x, w_attn, b_attn, out, present,
                                                    4096, 3072, 1024);
        attn64<<<dim3(16, 16, 4), 256, 0, stream>>>(out, present, a_ws);
        gemm64<1><<<dim3(16, 64), 256, 0, stream>>>(a_ws, w_proj, b_proj, out, nullptr,
                                                    4096, 1024, 1024);
    }
}

// Round 7
// 195.718 us; speedup vs baseline: 1.0921x; 1.0085x over previous
//
#include <hip/hip_runtime.h>
#include <hip/hip_bf16.h>

typedef __attribute__((ext_vector_type(8))) short short8;
typedef __attribute__((ext_vector_type(4))) float floatx4;

constexpr int Bsz = 4, Ssz = 1024, NXc = 1024, NHc = 16, HDc = 64;
constexpr int OUT_ELEMS  = Bsz * Ssz * NXc;        // 4194304
constexpr int HEAD_ELEMS = Bsz * NHc * Ssz * HDc;  // 4194304

union BF8 { __hip_bfloat16 h[8]; uint4 v; short8 s; };

__device__ __forceinline__ uint4 cvt8(const float* __restrict__ p) {
    float4 a = *reinterpret_cast<const float4*>(p);
    float4 b = *reinterpret_cast<const float4*>(p + 4);
    BF8 u;
    u.h[0] = __float2bfloat16(a.x); u.h[1] = __float2bfloat16(a.y);
    u.h[2] = __float2bfloat16(a.z); u.h[3] = __float2bfloat16(a.w);
    u.h[4] = __float2bfloat16(b.x); u.h[5] = __float2bfloat16(b.y);
    u.h[6] = __float2bfloat16(b.z); u.h[7] = __float2bfloat16(b.w);
    return u.v;
}

// async 16B global -> LDS (wave-uniform LDS base + lane*16)
__device__ __forceinline__ void load_lds_16B(const void* g, void* l) {
    __builtin_amdgcn_global_load_lds(
        (const __attribute__((address_space(1))) unsigned int*)g,
        (__attribute__((address_space(3))) unsigned int*)l, 16, 0, 0);
}

// ===========================================================================
// FAST PATH
// ===========================================================================

// Fused prep: x fp32->bf16 (blocks 0..2047), w_attn transpose (2048..2815),
// w_proj transpose (2816..3071).
__global__ __launch_bounds__(256) void prep_kernel(
    const float* __restrict__ x, __hip_bfloat16* __restrict__ x_bf,
    const float* __restrict__ w_attn, __hip_bfloat16* __restrict__ wTa,
    const float* __restrict__ w_proj, __hip_bfloat16* __restrict__ wTp)
{
    const int bid = blockIdx.x, tid = threadIdx.x;
    __shared__ float t[64][65];
    if (bid < 2048) {
        const int i = (bid * 256 + tid) * 8;   // covers exactly OUT_ELEMS
        *reinterpret_cast<uint4*>(x_bf + i) = cvt8(x + i);
        return;
    }
    const float* in; __hip_bfloat16* outp; int N, bx, by;
    if (bid < 2816) { const int q = bid - 2048; in = w_attn; outp = wTa; N = 3072; bx = q % 48; by = q / 48; }
    else            { const int q = bid - 2816; in = w_proj; outp = wTp; N = 1024; bx = q % 16; by = q / 16; }
    const int k0 = by * 64, n0 = bx * 64;
#pragma unroll
    for (int j = 0; j < 16; ++j) {
        const int idx = tid + j * 256;
        const int row = idx >> 6, col = idx & 63;
        t[row][col] = in[(size_t)(k0 + row) * N + n0 + col];
    }
    __syncthreads();
#pragma unroll
    for (int j = 0; j < 16; ++j) {
        const int idx = tid + j * 256;
        const int orow = idx >> 6, ocol = idx & 63;
        outp[(size_t)(n0 + orow) * 1024 + k0 + ocol] = __float2bfloat16(t[ocol][orow]);
    }
}

// ---------------------------------------------------------------------------
// 128x128-tile bf16 GEMM, BK=32. Depth-2 pipeline with 3 LDS buffers at
// ZERO extra LDS: {vmcnt(4) -> barrier -> issue stage(kt+2) into buffer
// (cb+2)%3 -> compute}. Post-barrier issue makes buffer (cb+2)%3 (== the
// one read during iter kt-1) provably quiescent. Counted vmcnt(4) only
// drains tile kt, which has had ~2 iterations of latency cover.
// LDS chunk-XOR swizzle (0 bank conflicts), setprio, XCD-bijective swizzle.
// EPI==0 epilogue also emits bf16 swizzled K/V tiles for attention.
// ---------------------------------------------------------------------------
template <int EPI>
__global__ __launch_bounds__(256) void gemm128p(
    const __hip_bfloat16* __restrict__ A,
    const __hip_bfloat16* __restrict__ Bt,
    const float* __restrict__ bias,
    float* __restrict__ outf,
    __hip_bfloat16* __restrict__ qws,
    float* __restrict__ present,
    __hip_bfloat16* __restrict__ kws,
    __hip_bfloat16* __restrict__ vtws,
    int M, int N, int K)
{
    __shared__ __align__(16) __hip_bfloat16 As[3][4096];
    __shared__ __align__(16) __hip_bfloat16 Bs[3][4096];

    const int nbx = N >> 7;
    const int nwg = (M >> 7) * nbx;
    const int wg  = blockIdx.x;
    const int swz = (wg & 7) * (nwg >> 3) + (wg >> 3);
    const int by  = swz / nbx, bx = swz % nbx;   // by-contiguous per XCD

    const int tid  = threadIdx.x;
    const int w    = tid >> 6, lane = tid & 63;
    const int quad = lane >> 4, l16 = lane & 15;
    const int m0 = by * 128, n0 = bx * 128;
    const int mb = (w >> 1) * 64, nbw = (w & 1) * 64;

    const int srow = lane >> 2;
    const int sksw = (((lane & 3) ^ ((lane >> 3) & 3))) * 8;
    const int rsw = (l16 >> 1) & 3;   // fragment-read swizzle

    floatx4 acc[4][4];
#pragma unroll
    for (int i = 0; i < 4; ++i)
#pragma unroll
        for (int j = 0; j < 4; ++j)
#pragma unroll
            for (int r = 0; r < 4; ++r) acc[i][j][r] = 0.f;

    auto stage = [&](int buf, int k0) {
#pragma unroll
        for (int c = 0; c < 2; ++c) {
            const int chunk = w * 2 + c;
            const int row = chunk * 16 + srow;
            load_lds_16B(A + (size_t)(m0 + row) * K + k0 + sksw,
                         &As[buf][chunk * 512]);
            load_lds_16B(Bt + (size_t)(n0 + row) * K + k0 + sksw,
                         &Bs[buf][chunk * 512]);
        }
    };

    stage(0, 0);
    stage(1, 32);
    int cb = 0;
    for (int k0 = 0; k0 < K; k0 += 32) {
        if (k0 + 32 < K) {
            asm volatile("s_waitcnt vmcnt(4)" ::: "memory");
        } else {
            asm volatile("s_waitcnt vmcnt(0)" ::: "memory");
        }
        __builtin_amdgcn_s_barrier();          // tile cb landed (all waves)
        __builtin_amdgcn_sched_barrier(0);

        if (k0 + 64 < K) {
            const int nb_ = (cb >= 1) ? cb - 1 : 2;   // (cb+2)%3, quiescent
            stage(nb_, k0 + 64);
        }

        short8 af[4], bfr[4];
#pragma unroll
        for (int mi = 0; mi < 4; ++mi)
            af[mi] = *reinterpret_cast<const short8*>(
                &As[cb][(mb + mi * 16 + l16) * 32 + ((quad ^ rsw) * 8)]);
#pragma unroll
        for (int ni = 0; ni < 4; ++ni)
            bfr[ni] = *reinterpret_cast<const short8*>(
                &Bs[cb][(nbw + ni * 16 + l16) * 32 + ((quad ^ rsw) * 8)]);
        __builtin_amdgcn_s_setprio(1);
#pragma unroll
        for (int mi = 0; mi < 4; ++mi)
#pragma unroll
            for (int ni = 0; ni < 4; ++ni)
                acc[mi][ni] = __builtin_amdgcn_mfma_f32_16x16x32_bf16(
                    af[mi], bfr[ni], acc[mi][ni], 0, 0, 0);
        __builtin_amdgcn_s_setprio(0);

        cb = (cb == 2) ? 0 : cb + 1;
    }

#pragma unroll
    for (int mi = 0; mi < 4; ++mi) {
#pragma unroll
        for (int ni = 0; ni < 4; ++ni) {
            const int col = n0 + nbw + ni * 16 + l16;
            const float bsv = bias[col];
#pragma unroll
            for (int r = 0; r < 4; ++r) {
                const int row = m0 + mb + mi * 16 + quad * 4 + r;
                const float v = acc[mi][ni][r] + bsv;
                if (EPI == 0) {
                    const int seg = col >> 10;  // 0=q 1=k 2=v
                    const int c = col & 1023;
                    if (seg == 0) {
                        qws[(size_t)row * 1024 + c] = __float2bfloat16(v);
                    } else {
                        const int bq = row >> 10, s = row & 1023;
                        const int hh = c >> 6, d = c & 63;
                        const size_t idx =
                            ((size_t)((bq * 16 + hh) * 1024 + s)) * 64 + d;
                        const int kt = s >> 6, key = s & 63;
                        const size_t tbase =
                            ((size_t)((bq * 16 + hh) * 16 + kt)) * 4096;
                        if (seg == 1) {
                            present[idx] = v;
                            // k_ws: [key][d], 16B-chunk swizzle seg^=key&7
                            kws[tbase + key * 64 +
                                ((((d >> 3) ^ (key & 7)) << 3) | (d & 7))] =
                                __float2bfloat16(v);
                        } else {
                            present[HEAD_ELEMS + idx] = v;
                            // vt_ws: [d][key], 16B-chunk swizzle seg^=d&7
                            vtws[tbase + d * 64 +
                                ((((key >> 3) ^ (d & 7)) << 3) | (key & 7))] =
                                __float2bfloat16(v);
                        }
                    }
                } else {
                    outf[(size_t)row * N + col] = v;
                }
            }
        }
    }
}

// ---------------------------------------------------------------------------
// Output projection GEMM: 128x64 tile, BK=32 -> 512 blocks (2/CU resident,
// 8 waves/CU vs the old 256-block 1/CU config). 4 waves, each owns a 32x64
// stripe (acc 2x4). 3 loads/wave/buffer (2 A-chunks + 1 B-chunk); depth-2
// 3-buffer pipeline with post-barrier staging; XOR swizzle; XCD swizzle.
// ---------------------------------------------------------------------------
__global__ __launch_bounds__(256) void gemm_proj(
    const __hip_bfloat16* __restrict__ A,     // a_ws bf16 [4096][1024]
    const __hip_bfloat16* __restrict__ Bt,    // wTp bf16 [1024][1024] (N-major)
    const float* __restrict__ bias,
    float* __restrict__ outf)                 // [4096][1024]
{
    constexpr int K = 1024, N = 1024;
    __shared__ __align__(16) __hip_bfloat16 As[3][4096];   // 128x32
    __shared__ __align__(16) __hip_bfloat16 Bs[3][2048];   // 64x32

    // 512 blocks: nbx=16, by in [0,32). XCD-bijective swizzle.
    const int wg  = blockIdx.x;
    const int swz = (wg & 7) * 64 + (wg >> 3);
    const int by  = swz >> 4, bx = swz & 15;

    const int tid  = threadIdx.x;
    const int w    = tid >> 6, lane = tid & 63;
    const int quad = lane >> 4, l16 = lane & 15;
    const int m0 = by * 128, n0 = bx * 64;
    const int mbase = w * 32;                 // wave's 32-row stripe

    const int srow = lane >> 2;
    const int sksw = (((lane & 3) ^ ((lane >> 3) & 3))) * 8;
    const int rsw = (l16 >> 1) & 3;

    floatx4 acc[2][4];
#pragma unroll
    for (int i = 0; i < 2; ++i)
#pragma unroll
        for (int j = 0; j < 4; ++j)
#pragma unroll
            for (int r = 0; r < 4; ++r) acc[i][j][r] = 0.f;

    auto stage = [&](int buf, int k0) {
#pragma unroll
        for (int c = 0; c < 2; ++c) {         // A: 8 chunks, wave does 2
            const int chunk = w * 2 + c;
            const int row = chunk * 16 + srow;
            load_lds_16B(A + (size_t)(m0 + row) * K + k0 + sksw,
                         &As[buf][chunk * 512]);
        }
        const int brow = w * 16 + srow;       // B: 4 chunks, wave does 1
        load_lds_16B(Bt + (size_t)(n0 + brow) * K + k0 + sksw,
                     &Bs[buf][w * 512]);
    };

    stage(0, 0);
    stage(1, 32);
    int cb = 0;
    for (int k0 = 0; k0 < K; k0 += 32) {
        if (k0 + 32 < K) {
            asm volatile("s_waitcnt vmcnt(3)" ::: "memory");
        } else {
            asm volatile("s_waitcnt vmcnt(0)" ::: "memory");
        }
        __builtin_amdgcn_s_barrier();
        __builtin_amdgcn_sched_barrier(0);

        if (k0 + 64 < K) {
            const int nb_ = (cb >= 1) ? cb - 1 : 2;   // (cb+2)%3, quiescent
            stage(nb_, k0 + 64);
        }

        short8 af[2], bfr[4];
#pragma unroll
        for (int mi = 0; mi < 2; ++mi)
            af[mi] = *reinterpret_cast<const short8*>(
                &As[cb][(mbase + mi * 16 + l16) * 32 + ((quad ^ rsw) * 8)]);
#pragma unroll
        for (int ni = 0; ni < 4; ++ni)
            bfr[ni] = *reinterpret_cast<const short8*>(
                &Bs[cb][(ni * 16 + l16) * 32 + ((quad ^ rsw) * 8)]);
        __builtin_amdgcn_s_setprio(1);
#pragma unroll
        for (int mi = 0; mi < 2; ++mi)
#pragma unroll
            for (int ni = 0; ni < 4; ++ni)
                acc[mi][ni] = __builtin_amdgcn_mfma_f32_16x16x32_bf16(
                    af[mi], bfr[ni], acc[mi][ni], 0, 0, 0);
        __builtin_amdgcn_s_setprio(0);

        cb = (cb == 2) ? 0 : cb + 1;
    }

#pragma unroll
    for (int mi = 0; mi < 2; ++mi) {
#pragma unroll
        for (int ni = 0; ni < 4; ++ni) {
            const int col = n0 + ni * 16 + l16;
            const float bsv = bias[col];
#pragma unroll
            for (int r = 0; r < 4; ++r) {
                const int row = m0 + mbase + mi * 16 + quad * 4 + r;
                outf[(size_t)row * N + col] = acc[mi][ni][r] + bsv;
            }
        }
    }
}

// ---------------------------------------------------------------------------
// Causal flash attention v6 (unchanged from round 6; proven).
// ---------------------------------------------------------------------------
__global__ __launch_bounds__(256) void attn_v6(
    const __hip_bfloat16* __restrict__ q_ws,
    const __hip_bfloat16* __restrict__ k_ws,
    const __hip_bfloat16* __restrict__ vt_ws,
    __hip_bfloat16* __restrict__ a_ws)
{
    const int wg  = blockIdx.x;
    const int swz = (wg & 7) * 64 + (wg >> 3);    // 512 blocks, bijective
    const int bx  = swz & 7;                      // q-pair index
    const int bh  = swz >> 3;                     // 8 consecutive heads/XCD
    const int b = bh >> 4, h = bh & 15;

    const int tid  = threadIdx.x;
    const int wave = tid >> 6, lane = tid & 63;
    const int quad = lane >> 4, l16 = lane & 15;
    const int stripe = wave * 16;                 // wave's 16 q-rows

    const __hip_bfloat16* Kbase = k_ws  + (size_t)bh * 65536;
    const __hip_bfloat16* Vbase = vt_ws + (size_t)bh * 65536;

    __shared__ __align__(16) __hip_bfloat16 Ksf[4][4096];   // [key][d] swz
    __shared__ __align__(16) __hip_bfloat16 Vsf[4][4096];   // [d][key] swz
    __shared__ __align__(16) __hip_bfloat16 Ps[64][72];     // [q][key]

    constexpr float SCL = 0.18033688011f;   // 0.125 * log2(e)

#pragma unroll
    for (int pass = 0; pass < 2; ++pass) {
        const int qt = (pass == 0) ? (8 + bx) : (7 - bx);

        // Q fragments in registers: rows stripe+l16, k = quad*8 (+32)
        const __hip_bfloat16* Qb =
            q_ws + ((size_t)(b * Ssz + qt * 64 + stripe + l16)) * NXc + h * 64;
        const short8 qf0 = *reinterpret_cast<const short8*>(Qb + quad * 8);
        const short8 qf1 = *reinterpret_cast<const short8*>(Qb + 32 + quad * 8);

        float m_i[4], l_i[4];
#pragma unroll
        for (int r = 0; r < 4; ++r) { m_i[r] = -1e9f; l_i[r] = 0.f; }
        floatx4 oacc[4];
#pragma unroll
        for (int ni = 0; ni < 4; ++ni)
#pragma unroll
            for (int r = 0; r < 4; ++r) oacc[ni][r] = 0.f;

        // ---- prologue: stage tiles 0 and 1 (depth-2) ----
#pragma unroll
        for (int c2 = 0; c2 < 2; ++c2) {
            const int c = wave + c2 * 4;
            load_lds_16B(Kbase + c * 512 + (lane << 3), &Ksf[0][c * 512]);
            load_lds_16B(Vbase + c * 512 + (lane << 3), &Vsf[0][c * 512]);
        }
        if (qt >= 1) {
#pragma unroll
            for (int c2 = 0; c2 < 2; ++c2) {
                const int c = wave + c2 * 4;
                load_lds_16B(Kbase + 4096 + c * 512 + (lane << 3),
                             &Ksf[1][c * 512]);
                load_lds_16B(Vbase + 4096 + c * 512 + (lane << 3),
                             &Vsf[1][c * 512]);
            }
        }

        for (int kt = 0; kt <= qt; ++kt) {
            const int cw = kt & 3;
            // ---- issue tile kt+2's loads; counted wait drains tile kt ----
            if (kt + 2 <= qt) {
                const int nb_ = (kt + 2) & 3;
                const __hip_bfloat16* Kt = Kbase + (size_t)(kt + 2) * 4096;
                const __hip_bfloat16* Vt = Vbase + (size_t)(kt + 2) * 4096;
#pragma unroll
                for (int c2 = 0; c2 < 2; ++c2) {
                    const int c = wave + c2 * 4;
                    load_lds_16B(Kt + c * 512 + (lane << 3), &Ksf[nb_][c * 512]);
                    load_lds_16B(Vt + c * 512 + (lane << 3), &Vsf[nb_][c * 512]);
                }
                asm volatile("s_waitcnt vmcnt(8)" ::: "memory");
            } else if (kt + 1 <= qt) {
                asm volatile("s_waitcnt vmcnt(4)" ::: "memory");
            } else {
                asm volatile("s_waitcnt vmcnt(0)" ::: "memory");
            }
            __builtin_amdgcn_s_barrier();        // all waves: tile kt landed
            __builtin_amdgcn_sched_barrier(0);

            // ---- S = Q K^T : wave's 16 rows x 64 keys ----
            floatx4 sacc[4];
#pragma unroll
            for (int ni = 0; ni < 4; ++ni)
#pragma unroll
                for (int r = 0; r < 4; ++r) sacc[ni][r] = 0.f;
            __builtin_amdgcn_s_setprio(1);
#pragma unroll
            for (int ni = 0; ni < 4; ++ni) {
                const int key = ni * 16 + l16;
                const int sw = key & 7;
                const short8 kf0 = *reinterpret_cast<const short8*>(
                    &Ksf[cw][key * 64 + ((quad ^ sw) << 3)]);
                const short8 kf1 = *reinterpret_cast<const short8*>(
                    &Ksf[cw][key * 64 + (((4 + quad) ^ sw) << 3)]);
                sacc[ni] = __builtin_amdgcn_mfma_f32_16x16x32_bf16(
                    qf0, kf0, sacc[ni], 0, 0, 0);
                sacc[ni] = __builtin_amdgcn_mfma_f32_16x16x32_bf16(
                    qf1, kf1, sacc[ni], 0, 0, 0);
            }
            __builtin_amdgcn_s_setprio(0);

            // ---- in-register online softmax, log2 domain ----
            const bool diag = (kt == qt);
            float alpha_[4];
#pragma unroll
            for (int r = 0; r < 4; ++r) {
                const int lrow = stripe + quad * 4 + r;
                float sv[4];
                float mx = -1e30f;
#pragma unroll
                for (int ni = 0; ni < 4; ++ni) {
                    float v = sacc[ni][r] * SCL;        // includes log2(e)
                    if (diag && (ni * 16 + l16) > lrow) v = -1e9f;
                    sv[ni] = v;
                    mx = fmaxf(mx, v);
                }
                mx = fmaxf(mx, __shfl_xor(mx, 1));
                mx = fmaxf(mx, __shfl_xor(mx, 2));
                mx = fmaxf(mx, __shfl_xor(mx, 4));
                mx = fmaxf(mx, __shfl_xor(mx, 8));
                const float mnew = fmaxf(m_i[r], mx);
                const float al = exp2f(m_i[r] - mnew);
                m_i[r] = mnew;
                float s = 0.f;
#pragma unroll
                for (int nn = 0; nn < 4; ++nn) {
                    const int ni = (nn + quad) & 3;     // bank-rotated stores
                    const float p = exp2f(sv[ni] - mnew);
                    s += p;
                    Ps[lrow][ni * 16 + l16] = __float2bfloat16(p);
                }
                s += __shfl_xor(s, 1);
                s += __shfl_xor(s, 2);
                s += __shfl_xor(s, 4);
                s += __shfl_xor(s, 8);
                l_i[r] = l_i[r] * al + s;
                alpha_[r] = al;
            }

            // rescale O (registers only)
#pragma unroll
            for (int ni = 0; ni < 4; ++ni)
#pragma unroll
                for (int r = 0; r < 4; ++r) oacc[ni][r] *= alpha_[r];

            // ---- O += P V : Ps rows written+read by this wave ----
            __builtin_amdgcn_s_setprio(1);
#pragma unroll
            for (int kk = 0; kk < 64; kk += 32) {
                const short8 pf = *reinterpret_cast<const short8*>(
                    &Ps[stripe + l16][kk + quad * 8]);
#pragma unroll
                for (int ni = 0; ni < 4; ++ni) {
                    const int d = ni * 16 + l16;
                    const int chunk = (kk >> 3) + quad;
                    const short8 vf = *reinterpret_cast<const short8*>(
                        &Vsf[cw][d * 64 + ((chunk ^ (d & 7)) << 3)]);
                    oacc[ni] = __builtin_amdgcn_mfma_f32_16x16x32_bf16(
                        pf, vf, oacc[ni], 0, 0, 0);
                }
            }
            __builtin_amdgcn_s_setprio(0);
        }

        // all waves done reading LDS before next pass's prologue staging
        __builtin_amdgcn_s_barrier();

        // ---- epilogue: O / l -> a_ws ----
#pragma unroll
        for (int ni = 0; ni < 4; ++ni) {
#pragma unroll
            for (int r = 0; r < 4; ++r) {
                const int row = qt * 64 + stripe + quad * 4 + r;
                const int col = h * 64 + ni * 16 + l16;
                const float inv = 1.0f / fmaxf(l_i[r], 1e-20f);
                a_ws[((size_t)(b * Ssz + row)) * NXc + col] =
                    __float2bfloat16(oacc[ni][r] * inv);
            }
        }
    }
}

// ===========================================================================
// FALLBACK PATH (round-3, known-passing; used if ws_size < 32 MB)
// ===========================================================================
template <int EPI>
__global__ __launch_bounds__(256) void gemm64(
    const void* __restrict__ Av, const float* __restrict__ Bw,
    const float* __restrict__ bias, float* __restrict__ out0,
    float* __restrict__ present, int M, int N, int K)
{
    __shared__ __align__(16) __hip_bfloat16 As[64][40];
    __shared__ __align__(16) __hip_bfloat16 Bs[64][40];
    const int tid = threadIdx.x;
    const int wave = tid >> 6, lane = tid & 63;
    const int quad = lane >> 4, l16 = lane & 15;
    const int m0 = blockIdx.y * 64, n0 = blockIdx.x * 64;
    const int mb = (wave >> 1) * 32, nb = (wave & 1) * 32;
    const int arow = tid >> 2, aseg = tid & 3;
    const int brow = tid >> 3, bseg = tid & 7;
    floatx4 acc[2][2];
#pragma unroll
    for (int i = 0; i < 2; ++i)
#pragma unroll
        for (int j = 0; j < 2; ++j)
#pragma unroll
            for (int r = 0; r < 4; ++r) acc[i][j][r] = 0.f;
    for (int k0 = 0; k0 < K; k0 += 32) {
        if (EPI == 0) {
            const float* A = (const float*)Av;
            *reinterpret_cast<uint4*>(&As[arow][aseg * 8]) =
                cvt8(A + (size_t)(m0 + arow) * K + k0 + aseg * 8);
        } else {
            const __hip_bfloat16* A = (const __hip_bfloat16*)Av;
            *reinterpret_cast<uint4*>(&As[arow][aseg * 8]) =
                *reinterpret_cast<const uint4*>(
                    A + (size_t)(m0 + arow) * K + k0 + aseg * 8);
        }
        const float* bp = Bw + (size_t)(k0 + brow) * N + n0 + bseg * 8;
        float4 b0 = *reinterpret_cast<const float4*>(bp);
        float4 b1 = *reinterpret_cast<const float4*>(bp + 4);
        Bs[bseg * 8 + 0][brow] = __float2bfloat16(b0.x);
        Bs[bseg * 8 + 1][brow] = __float2bfloat16(b0.y);
        Bs[bseg * 8 + 2][brow] = __float2bfloat16(b0.z);
        Bs[bseg * 8 + 3][brow] = __float2bfloat16(b0.w);
        Bs[bseg * 8 + 4][brow] = __float2bfloat16(b1.x);
        Bs[bseg * 8 + 5][brow] = __float2bfloat16(b1.y);
        Bs[bseg * 8 + 6][brow] = __float2bfloat16(b1.z);
        Bs[bseg * 8 + 7][brow] = __float2bfloat16(b1.w);
        __syncthreads();
        short8 af[2], bf[2];
#pragma unroll
        for (int mm = 0; mm < 2; ++mm)
            af[mm] = *reinterpret_cast<const short8*>(&As[mb + mm * 16 + l16][quad * 8]);
#pragma unroll
        for (int nn = 0; nn < 2; ++nn)
            bf[nn] = *reinterpret_cast<const short8*>(&Bs[nb + nn * 16 + l16][quad * 8]);
#pragma unroll
        for (int mm = 0; mm < 2; ++mm)
#pragma unroll
            for (int nn = 0; nn < 2; ++nn)
                acc[mm][nn] = __builtin_amdgcn_mfma_f32_16x16x32_bf16(
                    af[mm], bf[nn], acc[mm][nn], 0, 0, 0);
        __syncthreads();
    }
#pragma unroll
    for (int mm = 0; mm < 2; ++mm)
#pragma unroll
        for (int nn = 0; nn < 2; ++nn) {
            const int col = n0 + nb + nn * 16 + l16;
            const float bsv = bias[col];
#pragma unroll
            for (int r = 0; r < 4; ++r) {
                const int row = m0 + mb + mm * 16 + quad * 4 + r;
                const float v = acc[mm][nn][r] + bsv;
                if (EPI == 0) {
                    const int seg = col >> 10;
                    const int c = col & 1023;
                    if (seg == 0) out0[(size_t)row * 1024 + c] = v;
                    else {
                        const int b = row >> 10, s = row & 1023;
                        const int h = c >> 6, d = c & 63;
                        const size_t idx = ((size_t)((b * 16 + h) * 1024 + s)) * 64 + d;
                        if (seg == 1) present[idx] = v;
                        else          present[HEAD_ELEMS + idx] = v;
                    }
                } else out0[(size_t)row * N + col] = v;
            }
        }
}

__global__ __launch_bounds__(256) void attn64(
    const float* __restrict__ qbuf, const float* __restrict__ present,
    __hip_bfloat16* __restrict__ a_ws)
{
    const int qt = blockIdx.x, h = blockIdx.y, b = blockIdx.z;
    const int tid = threadIdx.x;
    const int wave = tid >> 6, lane = tid & 63;
    const int quad = lane >> 4, l16 = lane & 15;
    const int mb = (wave >> 1) * 32, nb = (wave & 1) * 32;
    const size_t headoff = ((size_t)(b * 16 + h)) * Ssz * HDc;
    const float* Qb = qbuf + ((size_t)(b * Ssz + qt * 64)) * NXc + h * 64;
    const float* Kp = present + headoff;
    const float* Vp = present + HEAD_ELEMS + headoff;
    __shared__ __align__(16) __hip_bfloat16 Qs[64][72];
    __shared__ __align__(16) __hip_bfloat16 Ks[64][72];
    __shared__ __align__(16) __hip_bfloat16 Vts[64][72];
    __shared__ __align__(16) __hip_bfloat16 Ps[64][72];
    __shared__ float Sc[64][65];
    __shared__ float mrow[64], lrow[64], arw[64];
#pragma unroll
    for (int it = 0; it < 2; ++it) {
        const int c = tid + it * 256;
        const int row = c >> 3, seg = c & 7;
        *reinterpret_cast<uint4*>(&Qs[row][seg * 8]) =
            cvt8(Qb + (size_t)row * NXc + seg * 8);
    }
    if (tid < 64) { mrow[tid] = -1e9f; lrow[tid] = 0.f; }
    floatx4 oacc[2][2];
#pragma unroll
    for (int i = 0; i < 2; ++i)
#pragma unroll
        for (int j = 0; j < 2; ++j)
#pragma unroll
            for (int r = 0; r < 4; ++r) oacc[i][j][r] = 0.f;
    __syncthreads();
    for (int kt = 0; kt <= qt; ++kt) {
#pragma unroll
        for (int it = 0; it < 2; ++it) {
            const int c = tid + it * 256;
            const int row = c >> 3, seg = c & 7;
            *reinterpret_cast<uint4*>(&Ks[row][seg * 8]) =
                cvt8(Kp + (size_t)(kt * 64 + row) * 64 + seg * 8);
            const float* vp = Vp + (size_t)(kt * 64 + row) * 64 + seg * 8;
            float4 v0 = *reinterpret_cast<const float4*>(vp);
            float4 v1 = *reinterpret_cast<const float4*>(vp + 4);
            Vts[seg * 8 + 0][row] = __float2bfloat16(v0.x);
            Vts[seg * 8 + 1][row] = __float2bfloat16(v0.y);
            Vts[seg * 8 + 2][row] = __float2bfloat16(v0.z);
            Vts[seg * 8 + 3][row] = __float2bfloat16(v0.w);
            Vts[seg * 8 + 4][row] = __float2bfloat16(v1.x);
            Vts[seg * 8 + 5][row] = __float2bfloat16(v1.y);
            Vts[seg * 8 + 6][row] = __float2bfloat16(v1.z);
            Vts[seg * 8 + 7][row] = __float2bfloat16(v1.w);
        }
        __syncthreads();
        floatx4 sacc[2][2];
#pragma unroll
        for (int i = 0; i < 2; ++i)
#pragma unroll
            for (int j = 0; j < 2; ++j)
#pragma unroll
                for (int r = 0; r < 4; ++r) sacc[i][j][r] = 0.f;
#pragma unroll
        for (int kd = 0; kd < 64; kd += 32) {
            short8 af[2], bf[2];
#pragma unroll
            for (int mm = 0; mm < 2; ++mm)
                af[mm] = *reinterpret_cast<const short8*>(&Qs[mb + mm * 16 + l16][kd + quad * 8]);
#pragma unroll
            for (int nn = 0; nn < 2; ++nn)
                bf[nn] = *reinterpret_cast<const short8*>(&Ks[nb + nn * 16 + l16][kd + quad * 8]);
#pragma unroll
            for (int mm = 0; mm < 2; ++mm)
#pragma unroll
                for (int nn = 0; nn < 2; ++nn)
                    sacc[mm][nn] = __builtin_amdgcn_mfma_f32_16x16x32_bf16(
                        af[mm], bf[nn], sacc[mm][nn], 0, 0, 0);
        }
        const bool diag = (kt == qt);
#pragma unroll
        for (int mm = 0; mm < 2; ++mm)
#pragma unroll
            for (int nn = 0; nn < 2; ++nn)
#pragma unroll
                for (int r = 0; r < 4; ++r) {
                    const int row = mb + mm * 16 + quad * 4 + r;
                    const int col = nb + nn * 16 + l16;
                    float v = fminf(fmaxf(sacc[mm][nn][r] * 0.125f, -1e8f), 1e8f);
                    if (diag && col > row) v = -1e9f;
                    Sc[row][col] = v;
                }
        __syncthreads();
        if (tid < 64) {
            const int r = tid;
            const float mo = mrow[r];
            float mx = mo;
            for (int c = 0; c < 64; ++c) mx = fmaxf(mx, Sc[r][c]);
            const float al = (mo <= -5e8f) ? 0.f : __expf(mo - mx);
            float sum = 0.f;
            for (int c = 0; c < 64; ++c) {
                const float sv = Sc[r][c];
                const float p = (sv <= -5e8f) ? 0.f : __expf(sv - mx);
                sum += p;
                Ps[r][c] = __float2bfloat16(p);
            }
            mrow[r] = mx;
            lrow[r] = lrow[r] * al + sum;
            arw[r]  = al;
        }
        __syncthreads();
#pragma unroll
        for (int mm = 0; mm < 2; ++mm) {
            const int rbase = mb + mm * 16 + quad * 4;
#pragma unroll
            for (int r = 0; r < 4; ++r) {
                const float al = arw[rbase + r];
                oacc[mm][0][r] *= al;
                oacc[mm][1][r] *= al;
            }
        }
#pragma unroll
        for (int kk = 0; kk < 64; kk += 32) {
            short8 pf[2], vf[2];
#pragma unroll
            for (int mm = 0; mm < 2; ++mm)
                pf[mm] = *reinterpret_cast<const short8*>(&Ps[mb + mm * 16 + l16][kk + quad * 8]);
#pragma unroll
            for (int nn = 0; nn < 2; ++nn)
                vf[nn] = *reinterpret_cast<const short8*>(&Vts[nb + nn * 16 + l16][kk + quad * 8]);
#pragma unroll
            for (int mm = 0; mm < 2; ++mm)
#pragma unroll
                for (int nn = 0; nn < 2; ++nn)
                    oacc[mm][nn] = __builtin_amdgcn_mfma_f32_16x16x32_bf16(
                        pf[mm], vf[nn], oacc[mm][nn], 0, 0, 0);
        }
        __syncthreads();
    }
#pragma unroll
    for (int mm = 0; mm < 2; ++mm)
#pragma unroll
        for (int nn = 0; nn < 2; ++nn)
#pragma unroll
            for (int r = 0; r < 4; ++r) {
                const int row = mb + mm * 16 + quad * 4 + r;
                const int col = nb + nn * 16 + l16;
                const float inv = 1.0f / fmaxf(lrow[row], 1e-20f);
                a_ws[((size_t)(b * Ssz + qt * 64 + row)) * NXc + h * 64 + col] =
                    __float2bfloat16(oacc[mm][nn][r] * inv);
            }
}

// ===========================================================================
extern "C" void kernel_launch(void* const* d_in, const int* in_sizes, int n_in,
                              void* d_out, int out_size, void* d_ws, size_t ws_size,
                              hipStream_t stream) {
    const float* x      = (const float*)d_in[0];
    const float* w_attn = (const float*)d_in[1];
    const float* b_attn = (const float*)d_in[2];
    const float* w_proj = (const float*)d_in[3];
    const float* b_proj = (const float*)d_in[4];

    float* out     = (float*)d_out;
    float* present = out + OUT_ELEMS;

    const size_t NEED = 32u * 1024u * 1024u;
    if (ws_size >= NEED) {
        // ws layout (bf16 elems):
        //   reg1 [0,4M)   : x_bf (dead after gemm128p<0>)
        //   reg2 [4M,8M)  : q_ws, then a_ws in-place (attn writes over q)
        //   reg3 [8M,12M) : unused
        //   wTa  [12M,15M): transposed w_attn
        //   wTp  [15M,16M): transposed w_proj
        // k_ws/vt_ws (8 MB each, bf16) live in the `out` region of d_out:
        // written by gemm128p<0>'s epilogue, read by attn_v6, dead before
        // gemm_proj overwrites out at the end.
        __hip_bfloat16* reg1 = (__hip_bfloat16*)d_ws;
        __hip_bfloat16* reg2 = reg1 + 4194304;
        __hip_bfloat16* reg3 = reg2 + 4194304;
        __hip_bfloat16* wTa  = reg3 + 4194304;
        __hip_bfloat16* wTp  = wTa + 3145728;
        __hip_bfloat16* kws  = (__hip_bfloat16*)out;
        __hip_bfloat16* vtws = kws + 4194304;

        prep_kernel<<<3072, 256, 0, stream>>>(x, reg1, w_attn, wTa, w_proj, wTp);

        gemm128p<0><<<768, 256, 0, stream>>>(
            reg1, wTa, b_attn, nullptr, reg2, present, kws, vtws,
            4096, 3072, 1024);

        attn_v6<<<512, 256, 0, stream>>>(reg2, kws, vtws, reg2);

        gemm_proj<<<512, 256, 0, stream>>>(reg2, wTp, b_proj, out);
    } else {
        // round-3 fallback (needs 8 MB ws)
        __hip_bfloat16* a_ws = (__hip_bfloat16*)d_ws;
        hipMemsetAsync(d_ws, 0, (size_t)OUT_ELEMS * sizeof(__hip_bfloat16), stream);
        gemm64<0><<<dim3(48, 64), 256, 0, stream>>>(x, w_attn, b_attn, out, present,
                                                    4096, 3072, 1024);
        attn64<<<dim3(16, 16, 4), 256, 0, stream>>>(out, present, a_ws);
        gemm64<1><<<dim3(16, 64), 256, 0, stream>>>(a_ws, w_proj, b_proj, out, nullptr,
                                                    4096, 1024, 1024);
    }
}